// Round 1
// baseline (6929.543 us; speedup 1.0000x reference)
//
#include <hip/hip_runtime.h>

// Sizes are fixed by the reference but derived from in_sizes at launch.
static constexpr int IN_F  = 128;
static constexpr int H_F   = 128;
static constexpr int OUT_F = 64;

// ---------------- degree ----------------
__global__ __launch_bounds__(256) void k_deg_count(const int* __restrict__ dst,
                                                   float* __restrict__ cnt, int E) {
    int i = blockIdx.x * 256 + threadIdx.x;
    if (i < E) atomicAdd(&cnt[dst[i]], 1.0f);
}

__global__ __launch_bounds__(256) void k_deg_final(float* __restrict__ dis,
                                                   float* __restrict__ di, int n) {
    int i = blockIdx.x * 256 + threadIdx.x;
    if (i < n) {
        float d = 1.0f + dis[i];   // deg includes self-loop
        dis[i] = rsqrtf(d);
        di[i]  = 1.0f / d;
    }
}

// ---------------- f32 GEMM, K=128, C[n x F] = A[n x 128] @ W[128 x F] ----------------
// block = 256 threads, 32 rows per block. A tile staged in LDS.
template <int F>
__global__ __launch_bounds__(256) void k_gemm_k128(const float* __restrict__ A,
                                                   const float* __restrict__ W,
                                                   float* __restrict__ C, int nrows) {
    __shared__ float As[32][128];
    const int tid  = threadIdx.x;
    const int row0 = blockIdx.x * 32;

    // load A tile: 1024 float4 slots, 4 per thread, coalesced
#pragma unroll
    for (int i = 0; i < 4; ++i) {
        int slot = tid + i * 256;       // 0..1023
        int r    = slot >> 5;           // /32
        int c4   = (slot & 31) * 4;
        float4 v = make_float4(0.f, 0.f, 0.f, 0.f);
        int gr = row0 + r;
        if (gr < nrows) v = *reinterpret_cast<const float4*>(A + (size_t)gr * 128 + c4);
        *reinterpret_cast<float4*>(&As[r][c4]) = v;
    }
    __syncthreads();

    constexpr int CG = F / 4;    // col groups of 4
    constexpr int RT = F / 32;   // rows per thread (4 for F=128, 2 for F=64)
    const int cg4 = (tid % CG) * 4;
    const int r0  = (tid / CG) * RT;

    float4 acc[RT];
#pragma unroll
    for (int i = 0; i < RT; ++i) acc[i] = make_float4(0.f, 0.f, 0.f, 0.f);

#pragma unroll
    for (int k = 0; k < 128; k += 4) {
        const float4 w0 = *reinterpret_cast<const float4*>(W + (k + 0) * F + cg4);
        const float4 w1 = *reinterpret_cast<const float4*>(W + (k + 1) * F + cg4);
        const float4 w2 = *reinterpret_cast<const float4*>(W + (k + 2) * F + cg4);
        const float4 w3 = *reinterpret_cast<const float4*>(W + (k + 3) * F + cg4);
#pragma unroll
        for (int rr = 0; rr < RT; ++rr) {
            const float4 a = *reinterpret_cast<const float4*>(&As[r0 + rr][k]);
            acc[rr].x += a.x * w0.x + a.y * w1.x + a.z * w2.x + a.w * w3.x;
            acc[rr].y += a.x * w0.y + a.y * w1.y + a.z * w2.y + a.w * w3.y;
            acc[rr].z += a.x * w0.z + a.y * w1.z + a.z * w2.z + a.w * w3.z;
            acc[rr].w += a.x * w0.w + a.y * w1.w + a.z * w2.w + a.w * w3.w;
        }
    }

#pragma unroll
    for (int rr = 0; rr < RT; ++rr) {
        int gr = row0 + r0 + rr;
        if (gr < nrows)
            *reinterpret_cast<float4*>(C + (size_t)gr * F + cg4) = acc[rr];
    }
}

// ---------------- edge scatter: agg[dst] += dis[src]*dis[dst] * h[src] ----------------
template <int F>
__global__ __launch_bounds__(256) void k_scatter(const int* __restrict__ src,
                                                 const int* __restrict__ dst,
                                                 const float* __restrict__ dis,
                                                 const float* __restrict__ h,
                                                 float* __restrict__ agg, int E) {
    constexpr int CH = F / 4;   // float4 chunks per edge
    int idx = blockIdx.x * 256 + threadIdx.x;
    int total = E * CH;
    if (idx >= total) return;
    int e  = idx / CH;
    int c4 = (idx % CH) * 4;
    int s = src[e], d = dst[e];
    float nrm = dis[s] * dis[d];
    const float4 v = *reinterpret_cast<const float4*>(h + (size_t)s * F + c4);
    float* ap = agg + (size_t)d * F + c4;
    atomicAdd(ap + 0, nrm * v.x);
    atomicAdd(ap + 1, nrm * v.y);
    atomicAdd(ap + 2, nrm * v.z);
    atomicAdd(ap + 3, nrm * v.w);
}

// ---------------- combine1: h = relu(agg + h1*di + b1), in-place over h1 ----------------
__global__ __launch_bounds__(256) void k_combine1(float* __restrict__ h1,
                                                  const float* __restrict__ agg,
                                                  const float* __restrict__ di,
                                                  const float* __restrict__ b, int n) {
    int idx = blockIdx.x * 256 + threadIdx.x;
    int total = n * 32;
    if (idx >= total) return;
    int row = idx >> 5;
    int c4  = (idx & 31) * 4;
    float dii = di[row];
    float4 hv = *reinterpret_cast<const float4*>(h1 + (size_t)row * 128 + c4);
    float4 av = *reinterpret_cast<const float4*>(agg + (size_t)row * 128 + c4);
    float4 bv = *reinterpret_cast<const float4*>(b + c4);
    float4 o;
    o.x = fmaxf(av.x + hv.x * dii + bv.x, 0.f);
    o.y = fmaxf(av.y + hv.y * dii + bv.y, 0.f);
    o.z = fmaxf(av.z + hv.z * dii + bv.z, 0.f);
    o.w = fmaxf(av.w + hv.w * dii + bv.w, 0.f);
    *reinterpret_cast<float4*>(h1 + (size_t)row * 128 + c4) = o;
}

// ---------------- fused MLP: z = relu(x@W1 + b1) @ W2 + b2 ----------------
__global__ __launch_bounds__(256) void k_mlp(const float* __restrict__ x,
                                             const float* __restrict__ W1,
                                             const float* __restrict__ b1,
                                             const float* __restrict__ W2,
                                             const float* __restrict__ b2,
                                             float* __restrict__ z, int nrows) {
    __shared__ float As[32][128];
    __shared__ float Ms[32][128];
    const int tid  = threadIdx.x;
    const int row0 = blockIdx.x * 32;

#pragma unroll
    for (int i = 0; i < 4; ++i) {
        int slot = tid + i * 256;
        int r    = slot >> 5;
        int c4   = (slot & 31) * 4;
        float4 v = make_float4(0.f, 0.f, 0.f, 0.f);
        int gr = row0 + r;
        if (gr < nrows) v = *reinterpret_cast<const float4*>(x + (size_t)gr * 128 + c4);
        *reinterpret_cast<float4*>(&As[r][c4]) = v;
    }
    __syncthreads();

    // phase 1: m1 = relu(x@W1 + b1) -> Ms (F=128)
    {
        const int cg4 = (tid & 31) * 4;
        const int r0  = (tid >> 5) * 4;
        float4 acc[4];
#pragma unroll
        for (int i = 0; i < 4; ++i) acc[i] = make_float4(0.f, 0.f, 0.f, 0.f);
#pragma unroll
        for (int k = 0; k < 128; k += 4) {
            const float4 w0 = *reinterpret_cast<const float4*>(W1 + (k + 0) * 128 + cg4);
            const float4 w1 = *reinterpret_cast<const float4*>(W1 + (k + 1) * 128 + cg4);
            const float4 w2 = *reinterpret_cast<const float4*>(W1 + (k + 2) * 128 + cg4);
            const float4 w3 = *reinterpret_cast<const float4*>(W1 + (k + 3) * 128 + cg4);
#pragma unroll
            for (int rr = 0; rr < 4; ++rr) {
                const float4 a = *reinterpret_cast<const float4*>(&As[r0 + rr][k]);
                acc[rr].x += a.x * w0.x + a.y * w1.x + a.z * w2.x + a.w * w3.x;
                acc[rr].y += a.x * w0.y + a.y * w1.y + a.z * w2.y + a.w * w3.y;
                acc[rr].z += a.x * w0.z + a.y * w1.z + a.z * w2.z + a.w * w3.z;
                acc[rr].w += a.x * w0.w + a.y * w1.w + a.z * w2.w + a.w * w3.w;
            }
        }
        const float4 bv = *reinterpret_cast<const float4*>(b1 + cg4);
#pragma unroll
        for (int rr = 0; rr < 4; ++rr) {
            float4 o;
            o.x = fmaxf(acc[rr].x + bv.x, 0.f);
            o.y = fmaxf(acc[rr].y + bv.y, 0.f);
            o.z = fmaxf(acc[rr].z + bv.z, 0.f);
            o.w = fmaxf(acc[rr].w + bv.w, 0.f);
            *reinterpret_cast<float4*>(&Ms[r0 + rr][cg4]) = o;
        }
    }
    __syncthreads();

    // phase 2: z = m1@W2 + b2 (F=64)
    {
        const int cg4 = (tid & 15) * 4;
        const int r0  = (tid >> 4) * 2;
        float4 acc[2];
        acc[0] = make_float4(0.f, 0.f, 0.f, 0.f);
        acc[1] = make_float4(0.f, 0.f, 0.f, 0.f);
#pragma unroll
        for (int k = 0; k < 128; k += 4) {
            const float4 w0 = *reinterpret_cast<const float4*>(W2 + (k + 0) * 64 + cg4);
            const float4 w1 = *reinterpret_cast<const float4*>(W2 + (k + 1) * 64 + cg4);
            const float4 w2 = *reinterpret_cast<const float4*>(W2 + (k + 2) * 64 + cg4);
            const float4 w3 = *reinterpret_cast<const float4*>(W2 + (k + 3) * 64 + cg4);
#pragma unroll
            for (int rr = 0; rr < 2; ++rr) {
                const float4 a = *reinterpret_cast<const float4*>(&Ms[r0 + rr][k]);
                acc[rr].x += a.x * w0.x + a.y * w1.x + a.z * w2.x + a.w * w3.x;
                acc[rr].y += a.x * w0.y + a.y * w1.y + a.z * w2.y + a.w * w3.y;
                acc[rr].z += a.x * w0.z + a.y * w1.z + a.z * w2.z + a.w * w3.z;
                acc[rr].w += a.x * w0.w + a.y * w1.w + a.z * w2.w + a.w * w3.w;
            }
        }
        const float4 bv = *reinterpret_cast<const float4*>(b2 + cg4);
#pragma unroll
        for (int rr = 0; rr < 2; ++rr) {
            int gr = row0 + r0 + rr;
            if (gr < nrows) {
                float4 o;
                o.x = acc[rr].x + bv.x;
                o.y = acc[rr].y + bv.y;
                o.z = acc[rr].z + bv.z;
                o.w = acc[rr].w + bv.w;
                *reinterpret_cast<float4*>(z + (size_t)gr * 64 + cg4) = o;
            }
        }
    }
}

// ---------------- final: out = 0.5*((agg2 + h2*di + gb2) + zmlp) ----------------
__global__ __launch_bounds__(256) void k_final(const float* __restrict__ h2,
                                               const float* __restrict__ agg2,
                                               const float* __restrict__ zmlp,
                                               const float* __restrict__ di,
                                               const float* __restrict__ gb2,
                                               float* __restrict__ out, int n) {
    int idx = blockIdx.x * 256 + threadIdx.x;
    int total = n * 16;
    if (idx >= total) return;
    int row = idx >> 4;
    int c4  = (idx & 15) * 4;
    float dii = di[row];
    float4 av = *reinterpret_cast<const float4*>(agg2 + (size_t)row * 64 + c4);
    float4 hv = *reinterpret_cast<const float4*>(h2 + (size_t)row * 64 + c4);
    float4 zm = *reinterpret_cast<const float4*>(zmlp + (size_t)row * 64 + c4);
    float4 bv = *reinterpret_cast<const float4*>(gb2 + c4);
    float4 o;
    o.x = 0.5f * ((av.x + hv.x * dii + bv.x) + zm.x);
    o.y = 0.5f * ((av.y + hv.y * dii + bv.y) + zm.y);
    o.z = 0.5f * ((av.z + hv.z * dii + bv.z) + zm.z);
    o.w = 0.5f * ((av.w + hv.w * dii + bv.w) + zm.w);
    *reinterpret_cast<float4*>(out + (size_t)row * 64 + c4) = o;
}

extern "C" void kernel_launch(void* const* d_in, const int* in_sizes, int n_in,
                              void* d_out, int out_size, void* d_ws, size_t ws_size,
                              hipStream_t stream) {
    const float* x      = (const float*)d_in[0];
    const int* edge_idx = (const int*)d_in[1];
    const float* gnn_W1 = (const float*)d_in[2];
    const float* gnn_b1 = (const float*)d_in[3];
    const float* gnn_W2 = (const float*)d_in[4];
    const float* gnn_b2 = (const float*)d_in[5];
    const float* mlp_W1 = (const float*)d_in[6];
    const float* mlp_b1 = (const float*)d_in[7];
    const float* mlp_W2 = (const float*)d_in[8];
    const float* mlp_b2 = (const float*)d_in[9];
    float* out = (float*)d_out;

    const int N = in_sizes[0] / IN_F;
    const int E = in_sizes[1] / 2;
    const int* src = edge_idx;
    const int* dst = edge_idx + E;

    // workspace layout (floats): dis[N] | di[N] | bufA[N*128] | bufB[N*128]
    float* w     = (float*)d_ws;
    float* w_dis = w;
    float* w_di  = w + N;
    float* bufA  = w + 2 * (size_t)N;             // h1 -> h (in-place) -> zmlp
    float* bufB  = bufA + (size_t)N * 128;        // agg1 -> {h2 | agg2}
    float* h2    = bufB;
    float* agg2  = bufB + (size_t)N * 64;
    float* zmlp  = bufA;

    // degree
    hipMemsetAsync(w_dis, 0, (size_t)N * sizeof(float), stream);
    k_deg_count<<<(E + 255) / 256, 256, 0, stream>>>(dst, w_dis, E);
    k_deg_final<<<(N + 255) / 256, 256, 0, stream>>>(w_dis, w_di, N);

    // GNN layer 1
    k_gemm_k128<128><<<(N + 31) / 32, 256, 0, stream>>>(x, gnn_W1, bufA, N);
    hipMemsetAsync(bufB, 0, (size_t)N * 128 * sizeof(float), stream);
    {
        long long total = (long long)E * 32;
        k_scatter<128><<<(unsigned)((total + 255) / 256), 256, 0, stream>>>(src, dst, w_dis, bufA, bufB, E);
    }
    k_combine1<<<(N * 32 + 255) / 256, 256, 0, stream>>>(bufA, bufB, w_di, gnn_b1, N);

    // GNN layer 2
    k_gemm_k128<64><<<(N + 31) / 32, 256, 0, stream>>>(bufA, gnn_W2, h2, N);
    hipMemsetAsync(agg2, 0, (size_t)N * 64 * sizeof(float), stream);
    {
        long long total = (long long)E * 16;
        k_scatter<64><<<(unsigned)((total + 255) / 256), 256, 0, stream>>>(src, dst, w_dis, h2, agg2, E);
    }

    // MLP branch (bufA free after GEMM2 consumed it)
    k_mlp<<<(N + 31) / 32, 256, 0, stream>>>(x, mlp_W1, mlp_b1, mlp_W2, mlp_b2, zmlp, N);

    // fuse
    k_final<<<(N * 16 + 255) / 256, 256, 0, stream>>>(h2, agg2, zmlp, w_di, gnn_b2, out, N);
}

// Round 2
// 3262.654 us; speedup vs baseline: 2.1239x; 2.1239x over previous
//
#include <hip/hip_runtime.h>

static constexpr int IN_F  = 128;

// ================= CSR build =================

__global__ __launch_bounds__(256) void k_hist(const int* __restrict__ dst,
                                              int* __restrict__ hist, int E) {
    int i = blockIdx.x * 256 + threadIdx.x;
    if (i < E) atomicAdd(&hist[dst[i]], 1);
}

// per-block exclusive scan of hist -> row_ptr(partial), block totals -> blockSums
__global__ __launch_bounds__(256) void k_scan1(const int* __restrict__ hist,
                                               int* __restrict__ row_ptr,
                                               int* __restrict__ blockSums, int n) {
    __shared__ int s[256];
    int tid = threadIdx.x;
    int i   = blockIdx.x * 256 + tid;
    int v   = (i < n) ? hist[i] : 0;
    s[tid] = v;
    __syncthreads();
    int inc = v;
#pragma unroll
    for (int off = 1; off < 256; off <<= 1) {
        int add = (tid >= off) ? s[tid - off] : 0;
        __syncthreads();
        s[tid] = inc = inc + add;
        __syncthreads();
    }
    if (i < n) row_ptr[i] = inc - v;           // exclusive
    if (tid == 255) blockSums[blockIdx.x] = inc;  // block total
}

// scan the block sums (nb <= 1024)
__global__ __launch_bounds__(1024) void k_scan2(int* __restrict__ blockSums, int nb) {
    __shared__ int s[1024];
    int tid = threadIdx.x;
    int v = (tid < nb) ? blockSums[tid] : 0;
    s[tid] = v;
    __syncthreads();
    int inc = v;
#pragma unroll
    for (int off = 1; off < 1024; off <<= 1) {
        int add = (tid >= off) ? s[tid - off] : 0;
        __syncthreads();
        s[tid] = inc = inc + add;
        __syncthreads();
    }
    if (tid < nb) blockSums[tid] = inc - v;    // exclusive
}

// add block offsets, emit dis[] = rsqrt(1+deg), row_ptr[N] = E
__global__ __launch_bounds__(256) void k_scan3(int* __restrict__ row_ptr,
                                               const int* __restrict__ blockSums,
                                               const int* __restrict__ hist,
                                               float* __restrict__ dis, int n, int E) {
    int i = blockIdx.x * 256 + threadIdx.x;
    if (i < n) {
        row_ptr[i] += blockSums[i >> 8];
        dis[i] = rsqrtf(1.0f + (float)hist[i]);
    }
    if (i == 0) row_ptr[n] = E;
}

// cursor[] starts as row_ptr[]; scatter src ids into CSR slots
__global__ __launch_bounds__(256) void k_fill(const int* __restrict__ src,
                                              const int* __restrict__ dst,
                                              int* __restrict__ cursor,
                                              int* __restrict__ csr_src, int E) {
    int e = blockIdx.x * 256 + threadIdx.x;
    if (e < E) {
        int slot = atomicAdd(&cursor[dst[e]], 1);
        csr_src[slot] = src[e];
    }
}

// ================= gather-side GCN aggregation =================
// layer 1: out = relu(dis[d] * sum_j dis[s_j]*h1[s_j] + h1[d]/deg + b1), F=128
__global__ __launch_bounds__(256) void k_agg1(const int* __restrict__ rp,
                                              const int* __restrict__ csrc,
                                              const float* __restrict__ dis,
                                              const float* __restrict__ h1,
                                              const float* __restrict__ b,
                                              float* __restrict__ out, int n) {
    const int lane = threadIdx.x & 63;
    const int node = blockIdx.x * 4 + (threadIdx.x >> 6);
    if (node >= n) return;
    const int start = rp[node], end = rp[node + 1];
    float ax = 0.f, ay = 0.f;
    for (int j = start; j < end; ++j) {
        int s = csrc[j];
        float w = dis[s];
        float2 v = *reinterpret_cast<const float2*>(h1 + (size_t)s * 128 + lane * 2);
        ax += w * v.x;
        ay += w * v.y;
    }
    const float dd = dis[node];
    const float di = 1.0f / (float)(end - start + 1);
    float2 hv = *reinterpret_cast<const float2*>(h1 + (size_t)node * 128 + lane * 2);
    float2 bv = *reinterpret_cast<const float2*>(b + lane * 2);
    float2 o;
    o.x = fmaxf(dd * ax + hv.x * di + bv.x, 0.f);
    o.y = fmaxf(dd * ay + hv.y * di + bv.y, 0.f);
    *reinterpret_cast<float2*>(out + (size_t)node * 128 + lane * 2) = o;
}

// layer 2 + final fuse: out = 0.5*((dis[d]*sum + h2[d]/deg + b2) + zmlp), F=64
__global__ __launch_bounds__(256) void k_agg2(const int* __restrict__ rp,
                                              const int* __restrict__ csrc,
                                              const float* __restrict__ dis,
                                              const float* __restrict__ h2,
                                              const float* __restrict__ b,
                                              const float* __restrict__ zmlp,
                                              float* __restrict__ out, int n) {
    const int lane = threadIdx.x & 63;
    const int node = blockIdx.x * 4 + (threadIdx.x >> 6);
    if (node >= n) return;
    const int start = rp[node], end = rp[node + 1];
    float acc = 0.f;
    for (int j = start; j < end; ++j) {
        int s = csrc[j];
        acc += dis[s] * h2[(size_t)s * 64 + lane];
    }
    const float dd = dis[node];
    const float di = 1.0f / (float)(end - start + 1);
    float hv = h2[(size_t)node * 64 + lane];
    float zg = dd * acc + hv * di + b[lane];
    out[(size_t)node * 64 + lane] = 0.5f * (zg + zmlp[(size_t)node * 64 + lane]);
}

// ================= f32 GEMM, K=128 (unchanged from R1) =================
template <int F>
__global__ __launch_bounds__(256) void k_gemm_k128(const float* __restrict__ A,
                                                   const float* __restrict__ W,
                                                   float* __restrict__ C, int nrows) {
    __shared__ float As[32][128];
    const int tid  = threadIdx.x;
    const int row0 = blockIdx.x * 32;

#pragma unroll
    for (int i = 0; i < 4; ++i) {
        int slot = tid + i * 256;
        int r    = slot >> 5;
        int c4   = (slot & 31) * 4;
        float4 v = make_float4(0.f, 0.f, 0.f, 0.f);
        int gr = row0 + r;
        if (gr < nrows) v = *reinterpret_cast<const float4*>(A + (size_t)gr * 128 + c4);
        *reinterpret_cast<float4*>(&As[r][c4]) = v;
    }
    __syncthreads();

    constexpr int CG = F / 4;
    constexpr int RT = F / 32;
    const int cg4 = (tid % CG) * 4;
    const int r0  = (tid / CG) * RT;

    float4 acc[RT];
#pragma unroll
    for (int i = 0; i < RT; ++i) acc[i] = make_float4(0.f, 0.f, 0.f, 0.f);

#pragma unroll
    for (int k = 0; k < 128; k += 4) {
        const float4 w0 = *reinterpret_cast<const float4*>(W + (k + 0) * F + cg4);
        const float4 w1 = *reinterpret_cast<const float4*>(W + (k + 1) * F + cg4);
        const float4 w2 = *reinterpret_cast<const float4*>(W + (k + 2) * F + cg4);
        const float4 w3 = *reinterpret_cast<const float4*>(W + (k + 3) * F + cg4);
#pragma unroll
        for (int rr = 0; rr < RT; ++rr) {
            const float4 a = *reinterpret_cast<const float4*>(&As[r0 + rr][k]);
            acc[rr].x += a.x * w0.x + a.y * w1.x + a.z * w2.x + a.w * w3.x;
            acc[rr].y += a.x * w0.y + a.y * w1.y + a.z * w2.y + a.w * w3.y;
            acc[rr].z += a.x * w0.z + a.y * w1.z + a.z * w2.z + a.w * w3.z;
            acc[rr].w += a.x * w0.w + a.y * w1.w + a.z * w2.w + a.w * w3.w;
        }
    }

#pragma unroll
    for (int rr = 0; rr < RT; ++rr) {
        int gr = row0 + r0 + rr;
        if (gr < nrows)
            *reinterpret_cast<float4*>(C + (size_t)gr * F + cg4) = acc[rr];
    }
}

// ================= fused MLP (unchanged from R1) =================
__global__ __launch_bounds__(256) void k_mlp(const float* __restrict__ x,
                                             const float* __restrict__ W1,
                                             const float* __restrict__ b1,
                                             const float* __restrict__ W2,
                                             const float* __restrict__ b2,
                                             float* __restrict__ z, int nrows) {
    __shared__ float As[32][128];
    __shared__ float Ms[32][128];
    const int tid  = threadIdx.x;
    const int row0 = blockIdx.x * 32;

#pragma unroll
    for (int i = 0; i < 4; ++i) {
        int slot = tid + i * 256;
        int r    = slot >> 5;
        int c4   = (slot & 31) * 4;
        float4 v = make_float4(0.f, 0.f, 0.f, 0.f);
        int gr = row0 + r;
        if (gr < nrows) v = *reinterpret_cast<const float4*>(x + (size_t)gr * 128 + c4);
        *reinterpret_cast<float4*>(&As[r][c4]) = v;
    }
    __syncthreads();

    {
        const int cg4 = (tid & 31) * 4;
        const int r0  = (tid >> 5) * 4;
        float4 acc[4];
#pragma unroll
        for (int i = 0; i < 4; ++i) acc[i] = make_float4(0.f, 0.f, 0.f, 0.f);
#pragma unroll
        for (int k = 0; k < 128; k += 4) {
            const float4 w0 = *reinterpret_cast<const float4*>(W1 + (k + 0) * 128 + cg4);
            const float4 w1 = *reinterpret_cast<const float4*>(W1 + (k + 1) * 128 + cg4);
            const float4 w2 = *reinterpret_cast<const float4*>(W1 + (k + 2) * 128 + cg4);
            const float4 w3 = *reinterpret_cast<const float4*>(W1 + (k + 3) * 128 + cg4);
#pragma unroll
            for (int rr = 0; rr < 4; ++rr) {
                const float4 a = *reinterpret_cast<const float4*>(&As[r0 + rr][k]);
                acc[rr].x += a.x * w0.x + a.y * w1.x + a.z * w2.x + a.w * w3.x;
                acc[rr].y += a.x * w0.y + a.y * w1.y + a.z * w2.y + a.w * w3.y;
                acc[rr].z += a.x * w0.z + a.y * w1.z + a.z * w2.z + a.w * w3.z;
                acc[rr].w += a.x * w0.w + a.y * w1.w + a.z * w2.w + a.w * w3.w;
            }
        }
        const float4 bv = *reinterpret_cast<const float4*>(b1 + cg4);
#pragma unroll
        for (int rr = 0; rr < 4; ++rr) {
            float4 o;
            o.x = fmaxf(acc[rr].x + bv.x, 0.f);
            o.y = fmaxf(acc[rr].y + bv.y, 0.f);
            o.z = fmaxf(acc[rr].z + bv.z, 0.f);
            o.w = fmaxf(acc[rr].w + bv.w, 0.f);
            *reinterpret_cast<float4*>(&Ms[r0 + rr][cg4]) = o;
        }
    }
    __syncthreads();

    {
        const int cg4 = (tid & 15) * 4;
        const int r0  = (tid >> 4) * 2;
        float4 acc[2];
        acc[0] = make_float4(0.f, 0.f, 0.f, 0.f);
        acc[1] = make_float4(0.f, 0.f, 0.f, 0.f);
#pragma unroll
        for (int k = 0; k < 128; k += 4) {
            const float4 w0 = *reinterpret_cast<const float4*>(W2 + (k + 0) * 64 + cg4);
            const float4 w1 = *reinterpret_cast<const float4*>(W2 + (k + 1) * 64 + cg4);
            const float4 w2 = *reinterpret_cast<const float4*>(W2 + (k + 2) * 64 + cg4);
            const float4 w3 = *reinterpret_cast<const float4*>(W2 + (k + 3) * 64 + cg4);
#pragma unroll
            for (int rr = 0; rr < 2; ++rr) {
                const float4 a = *reinterpret_cast<const float4*>(&Ms[r0 + rr][k]);
                acc[rr].x += a.x * w0.x + a.y * w1.x + a.z * w2.x + a.w * w3.x;
                acc[rr].y += a.x * w0.y + a.y * w1.y + a.z * w2.y + a.w * w3.y;
                acc[rr].z += a.x * w0.z + a.y * w1.z + a.z * w2.z + a.w * w3.z;
                acc[rr].w += a.x * w0.w + a.y * w1.w + a.z * w2.w + a.w * w3.w;
            }
        }
        const float4 bv = *reinterpret_cast<const float4*>(b2 + cg4);
#pragma unroll
        for (int rr = 0; rr < 2; ++rr) {
            int gr = row0 + r0 + rr;
            if (gr < nrows) {
                float4 o;
                o.x = acc[rr].x + bv.x;
                o.y = acc[rr].y + bv.y;
                o.z = acc[rr].z + bv.z;
                o.w = acc[rr].w + bv.w;
                *reinterpret_cast<float4*>(z + (size_t)gr * 64 + cg4) = o;
            }
        }
    }
}

extern "C" void kernel_launch(void* const* d_in, const int* in_sizes, int n_in,
                              void* d_out, int out_size, void* d_ws, size_t ws_size,
                              hipStream_t stream) {
    const float* x      = (const float*)d_in[0];
    const int* edge_idx = (const int*)d_in[1];
    const float* gnn_W1 = (const float*)d_in[2];
    const float* gnn_b1 = (const float*)d_in[3];
    const float* gnn_W2 = (const float*)d_in[4];
    const float* gnn_b2 = (const float*)d_in[5];
    const float* mlp_W1 = (const float*)d_in[6];
    const float* mlp_b1 = (const float*)d_in[7];
    const float* mlp_W2 = (const float*)d_in[8];
    const float* mlp_b2 = (const float*)d_in[9];
    float* out = (float*)d_out;

    const int N = in_sizes[0] / IN_F;
    const int E = in_sizes[1] / 2;
    const int* src = edge_idx;
    const int* dst = edge_idx + E;

    const int nb1 = (N + 255) / 256;   // scan blocks (391 for N=100000, <=1024 ok)

    // ---- workspace layout ----
    // ints:  row_ptr[N+1] | hist_cur[N] | csr_src[E] | blockSums[1024]
    // floats: dis[N] | bufA[N*128] | bufB[N*128]
    char* wp = (char*)d_ws;
    int* row_ptr   = (int*)wp;            wp += ((size_t)N + 4) * sizeof(int);
    int* hist_cur  = (int*)wp;            wp += (size_t)N * sizeof(int);
    int* csr_src   = (int*)wp;            wp += (size_t)E * sizeof(int);
    int* blockSums = (int*)wp;            wp += 1024 * sizeof(int);
    float* dis     = (float*)wp;          wp += (size_t)N * sizeof(float);
    float* bufA    = (float*)wp;          wp += (size_t)N * 128 * sizeof(float);
    float* bufB    = (float*)wp;          wp += (size_t)N * 128 * sizeof(float);

    // ---- CSR build ----
    hipMemsetAsync(hist_cur, 0, (size_t)N * sizeof(int), stream);
    k_hist<<<(E + 255) / 256, 256, 0, stream>>>(dst, hist_cur, E);
    k_scan1<<<nb1, 256, 0, stream>>>(hist_cur, row_ptr, blockSums, N);
    k_scan2<<<1, 1024, 0, stream>>>(blockSums, nb1);
    k_scan3<<<nb1, 256, 0, stream>>>(row_ptr, blockSums, hist_cur, dis, N, E);
    hipMemcpyAsync(hist_cur, row_ptr, (size_t)N * sizeof(int),
                   hipMemcpyDeviceToDevice, stream);   // cursor = row_ptr
    k_fill<<<(E + 255) / 256, 256, 0, stream>>>(src, dst, hist_cur, csr_src, E);

    // ---- GNN layer 1 ----
    k_gemm_k128<128><<<(N + 31) / 32, 256, 0, stream>>>(x, gnn_W1, bufA, N);   // h1
    k_agg1<<<(N + 3) / 4, 256, 0, stream>>>(row_ptr, csr_src, dis, bufA, gnn_b1, bufB, N); // h

    // ---- GNN layer 2 (matmul) ----
    k_gemm_k128<64><<<(N + 31) / 32, 256, 0, stream>>>(bufB, gnn_W2, bufA, N); // h2 -> bufA

    // ---- MLP branch (bufB free now) ----
    k_mlp<<<(N + 31) / 32, 256, 0, stream>>>(x, mlp_W1, mlp_b1, mlp_W2, mlp_b2, bufB, N); // zmlp

    // ---- layer-2 aggregation fused with final mix ----
    k_agg2<<<(N + 3) / 4, 256, 0, stream>>>(row_ptr, csr_src, dis, bufA, gnn_b2, bufB, out, N);
}

// Round 3
// 773.945 us; speedup vs baseline: 8.9535x; 4.2156x over previous
//
#include <hip/hip_runtime.h>

static constexpr int IN_F  = 128;

// ================= CSR build =================

__global__ __launch_bounds__(256) void k_hist(const int* __restrict__ dst,
                                              int* __restrict__ hist, int E) {
    int i = blockIdx.x * 256 + threadIdx.x;
    if (i < E) atomicAdd(&hist[dst[i]], 1);
}

// per-block exclusive scan of hist -> row_ptr(partial), block totals -> blockSums
__global__ __launch_bounds__(256) void k_scan1(const int* __restrict__ hist,
                                               int* __restrict__ row_ptr,
                                               int* __restrict__ blockSums, int n) {
    __shared__ int s[256];
    int tid = threadIdx.x;
    int i   = blockIdx.x * 256 + tid;
    int v   = (i < n) ? hist[i] : 0;
    s[tid] = v;
    __syncthreads();
    int inc = v;
#pragma unroll
    for (int off = 1; off < 256; off <<= 1) {
        int add = (tid >= off) ? s[tid - off] : 0;
        __syncthreads();
        s[tid] = inc = inc + add;
        __syncthreads();
    }
    if (i < n) row_ptr[i] = inc - v;           // exclusive
    if (tid == 255) blockSums[blockIdx.x] = inc;  // block total
}

// scan the block sums (nb <= 1024)
__global__ __launch_bounds__(1024) void k_scan2(int* __restrict__ blockSums, int nb) {
    __shared__ int s[1024];
    int tid = threadIdx.x;
    int v = (tid < nb) ? blockSums[tid] : 0;
    s[tid] = v;
    __syncthreads();
    int inc = v;
#pragma unroll
    for (int off = 1; off < 1024; off <<= 1) {
        int add = (tid >= off) ? s[tid - off] : 0;
        __syncthreads();
        s[tid] = inc = inc + add;
        __syncthreads();
    }
    if (tid < nb) blockSums[tid] = inc - v;    // exclusive
}

// add block offsets, emit dis[] = rsqrt(1+deg), cursor = row_ptr, row_ptr[N] = E
__global__ __launch_bounds__(256) void k_scan3(int* __restrict__ row_ptr,
                                               const int* __restrict__ blockSums,
                                               const int* __restrict__ hist,
                                               int* __restrict__ cursor,
                                               float* __restrict__ dis, int n, int E) {
    int i = blockIdx.x * 256 + threadIdx.x;
    if (i < n) {
        int rp = row_ptr[i] + blockSums[i >> 8];
        row_ptr[i] = rp;
        cursor[i]  = rp;
        dis[i] = rsqrtf(1.0f + (float)hist[i]);
    }
    if (i == 0) row_ptr[n] = E;
}

// scatter src ids into CSR slots
__global__ __launch_bounds__(256) void k_fill(const int* __restrict__ src,
                                              const int* __restrict__ dst,
                                              int* __restrict__ cursor,
                                              int* __restrict__ csr_src, int E) {
    int e = blockIdx.x * 256 + threadIdx.x;
    if (e < E) {
        int slot = atomicAdd(&cursor[dst[e]], 1);
        csr_src[slot] = src[e];
    }
}

// ================= gather-side GCN aggregation =================
// layer 1: out = relu(dis[d] * sum_j dis[s_j]*h1[s_j] + h1[d]/deg + b1), F=128
__global__ __launch_bounds__(256) void k_agg1(const int* __restrict__ rp,
                                              const int* __restrict__ csrc,
                                              const float* __restrict__ dis,
                                              const float* __restrict__ h1,
                                              const float* __restrict__ b,
                                              float* __restrict__ out, int n) {
    const int lane = threadIdx.x & 63;
    const int node = blockIdx.x * 4 + (threadIdx.x >> 6);
    if (node >= n) return;
    const int start = rp[node], end = rp[node + 1];
    float ax = 0.f, ay = 0.f;
    for (int j = start; j < end; ++j) {
        int s = csrc[j];
        float w = dis[s];
        float2 v = *reinterpret_cast<const float2*>(h1 + (size_t)s * 128 + lane * 2);
        ax += w * v.x;
        ay += w * v.y;
    }
    const float dd = dis[node];
    const float di = 1.0f / (float)(end - start + 1);
    float2 hv = *reinterpret_cast<const float2*>(h1 + (size_t)node * 128 + lane * 2);
    float2 bv = *reinterpret_cast<const float2*>(b + lane * 2);
    float2 o;
    o.x = fmaxf(dd * ax + hv.x * di + bv.x, 0.f);
    o.y = fmaxf(dd * ay + hv.y * di + bv.y, 0.f);
    *reinterpret_cast<float2*>(out + (size_t)node * 128 + lane * 2) = o;
}

// layer 2 + final fuse: out = 0.5*((dis[d]*sum + h2[d]/deg + b2) + zmlp), F=64
__global__ __launch_bounds__(256) void k_agg2(const int* __restrict__ rp,
                                              const int* __restrict__ csrc,
                                              const float* __restrict__ dis,
                                              const float* __restrict__ h2,
                                              const float* __restrict__ b,
                                              const float* __restrict__ zmlp,
                                              float* __restrict__ out, int n) {
    const int lane = threadIdx.x & 63;
    const int node = blockIdx.x * 4 + (threadIdx.x >> 6);
    if (node >= n) return;
    const int start = rp[node], end = rp[node + 1];
    float acc = 0.f;
    for (int j = start; j < end; ++j) {
        int s = csrc[j];
        acc += dis[s] * h2[(size_t)s * 64 + lane];
    }
    const float dd = dis[node];
    const float di = 1.0f / (float)(end - start + 1);
    float hv = h2[(size_t)node * 64 + lane];
    float zg = dd * acc + hv * di + b[lane];
    out[(size_t)node * 64 + lane] = 0.5f * (zg + zmlp[(size_t)node * 64 + lane]);
}

// ================= f32 GEMM, K=128 — unroll capped to avoid spills =================
template <int F>
__global__ __launch_bounds__(256) void k_gemm_k128(const float* __restrict__ A,
                                                   const float* __restrict__ W,
                                                   float* __restrict__ C, int nrows) {
    __shared__ float As[32][128];
    const int tid  = threadIdx.x;
    const int row0 = blockIdx.x * 32;

#pragma unroll
    for (int i = 0; i < 4; ++i) {
        int slot = tid + i * 256;
        int r    = slot >> 5;
        int c4   = (slot & 31) * 4;
        float4 v = make_float4(0.f, 0.f, 0.f, 0.f);
        int gr = row0 + r;
        if (gr < nrows) v = *reinterpret_cast<const float4*>(A + (size_t)gr * 128 + c4);
        *reinterpret_cast<float4*>(&As[r][c4]) = v;
    }
    __syncthreads();

    constexpr int CG = F / 4;
    constexpr int RT = F / 32;
    const int cg4 = (tid % CG) * 4;
    const int r0  = (tid / CG) * RT;

    float4 acc[RT];
#pragma unroll
    for (int i = 0; i < RT; ++i) acc[i] = make_float4(0.f, 0.f, 0.f, 0.f);

#pragma unroll 4
    for (int k = 0; k < 128; k += 4) {
        const float4 w0 = *reinterpret_cast<const float4*>(W + (k + 0) * F + cg4);
        const float4 w1 = *reinterpret_cast<const float4*>(W + (k + 1) * F + cg4);
        const float4 w2 = *reinterpret_cast<const float4*>(W + (k + 2) * F + cg4);
        const float4 w3 = *reinterpret_cast<const float4*>(W + (k + 3) * F + cg4);
#pragma unroll
        for (int rr = 0; rr < RT; ++rr) {
            const float4 a = *reinterpret_cast<const float4*>(&As[r0 + rr][k]);
            acc[rr].x += a.x * w0.x + a.y * w1.x + a.z * w2.x + a.w * w3.x;
            acc[rr].y += a.x * w0.y + a.y * w1.y + a.z * w2.y + a.w * w3.y;
            acc[rr].z += a.x * w0.z + a.y * w1.z + a.z * w2.z + a.w * w3.z;
            acc[rr].w += a.x * w0.w + a.y * w1.w + a.z * w2.w + a.w * w3.w;
        }
    }

#pragma unroll
    for (int rr = 0; rr < RT; ++rr) {
        int gr = row0 + r0 + rr;
        if (gr < nrows)
            *reinterpret_cast<float4*>(C + (size_t)gr * F + cg4) = acc[rr];
    }
}

// ================= fused MLP: z = relu(x@W1 + b1) @ W2 + b2 =================
__global__ __launch_bounds__(256) void k_mlp(const float* __restrict__ x,
                                             const float* __restrict__ W1,
                                             const float* __restrict__ b1,
                                             const float* __restrict__ W2,
                                             const float* __restrict__ b2,
                                             float* __restrict__ z, int nrows) {
    __shared__ float As[32][128];
    __shared__ float Ms[32][128];
    const int tid  = threadIdx.x;
    const int row0 = blockIdx.x * 32;

#pragma unroll
    for (int i = 0; i < 4; ++i) {
        int slot = tid + i * 256;
        int r    = slot >> 5;
        int c4   = (slot & 31) * 4;
        float4 v = make_float4(0.f, 0.f, 0.f, 0.f);
        int gr = row0 + r;
        if (gr < nrows) v = *reinterpret_cast<const float4*>(x + (size_t)gr * 128 + c4);
        *reinterpret_cast<float4*>(&As[r][c4]) = v;
    }
    __syncthreads();

    // phase 1: m1 = relu(x@W1 + b1) -> Ms
    {
        const int cg4 = (tid & 31) * 4;
        const int r0  = (tid >> 5) * 4;
        float4 acc[4];
#pragma unroll
        for (int i = 0; i < 4; ++i) acc[i] = make_float4(0.f, 0.f, 0.f, 0.f);
#pragma unroll 4
        for (int k = 0; k < 128; k += 4) {
            const float4 w0 = *reinterpret_cast<const float4*>(W1 + (k + 0) * 128 + cg4);
            const float4 w1 = *reinterpret_cast<const float4*>(W1 + (k + 1) * 128 + cg4);
            const float4 w2 = *reinterpret_cast<const float4*>(W1 + (k + 2) * 128 + cg4);
            const float4 w3 = *reinterpret_cast<const float4*>(W1 + (k + 3) * 128 + cg4);
#pragma unroll
            for (int rr = 0; rr < 4; ++rr) {
                const float4 a = *reinterpret_cast<const float4*>(&As[r0 + rr][k]);
                acc[rr].x += a.x * w0.x + a.y * w1.x + a.z * w2.x + a.w * w3.x;
                acc[rr].y += a.x * w0.y + a.y * w1.y + a.z * w2.y + a.w * w3.y;
                acc[rr].z += a.x * w0.z + a.y * w1.z + a.z * w2.z + a.w * w3.z;
                acc[rr].w += a.x * w0.w + a.y * w1.w + a.z * w2.w + a.w * w3.w;
            }
        }
        const float4 bv = *reinterpret_cast<const float4*>(b1 + cg4);
#pragma unroll
        for (int rr = 0; rr < 4; ++rr) {
            float4 o;
            o.x = fmaxf(acc[rr].x + bv.x, 0.f);
            o.y = fmaxf(acc[rr].y + bv.y, 0.f);
            o.z = fmaxf(acc[rr].z + bv.z, 0.f);
            o.w = fmaxf(acc[rr].w + bv.w, 0.f);
            *reinterpret_cast<float4*>(&Ms[r0 + rr][cg4]) = o;
        }
    }
    __syncthreads();

    // phase 2: z = m1@W2 + b2 (F=64)
    {
        const int cg4 = (tid & 15) * 4;
        const int r0  = (tid >> 4) * 2;
        float4 acc[2];
        acc[0] = make_float4(0.f, 0.f, 0.f, 0.f);
        acc[1] = make_float4(0.f, 0.f, 0.f, 0.f);
#pragma unroll 4
        for (int k = 0; k < 128; k += 4) {
            const float4 w0 = *reinterpret_cast<const float4*>(W2 + (k + 0) * 64 + cg4);
            const float4 w1 = *reinterpret_cast<const float4*>(W2 + (k + 1) * 64 + cg4);
            const float4 w2 = *reinterpret_cast<const float4*>(W2 + (k + 2) * 64 + cg4);
            const float4 w3 = *reinterpret_cast<const float4*>(W2 + (k + 3) * 64 + cg4);
#pragma unroll
            for (int rr = 0; rr < 2; ++rr) {
                const float4 a = *reinterpret_cast<const float4*>(&Ms[r0 + rr][k]);
                acc[rr].x += a.x * w0.x + a.y * w1.x + a.z * w2.x + a.w * w3.x;
                acc[rr].y += a.x * w0.y + a.y * w1.y + a.z * w2.y + a.w * w3.y;
                acc[rr].z += a.x * w0.z + a.y * w1.z + a.z * w2.z + a.w * w3.z;
                acc[rr].w += a.x * w0.w + a.y * w1.w + a.z * w2.w + a.w * w3.w;
            }
        }
        const float4 bv = *reinterpret_cast<const float4*>(b2 + cg4);
#pragma unroll
        for (int rr = 0; rr < 2; ++rr) {
            int gr = row0 + r0 + rr;
            if (gr < nrows) {
                float4 o;
                o.x = acc[rr].x + bv.x;
                o.y = acc[rr].y + bv.y;
                o.z = acc[rr].z + bv.z;
                o.w = acc[rr].w + bv.w;
                *reinterpret_cast<float4*>(z + (size_t)gr * 64 + cg4) = o;
            }
        }
    }
}

extern "C" void kernel_launch(void* const* d_in, const int* in_sizes, int n_in,
                              void* d_out, int out_size, void* d_ws, size_t ws_size,
                              hipStream_t stream) {
    const float* x      = (const float*)d_in[0];
    const int* edge_idx = (const int*)d_in[1];
    const float* gnn_W1 = (const float*)d_in[2];
    const float* gnn_b1 = (const float*)d_in[3];
    const float* gnn_W2 = (const float*)d_in[4];
    const float* gnn_b2 = (const float*)d_in[5];
    const float* mlp_W1 = (const float*)d_in[6];
    const float* mlp_b1 = (const float*)d_in[7];
    const float* mlp_W2 = (const float*)d_in[8];
    const float* mlp_b2 = (const float*)d_in[9];
    float* out = (float*)d_out;

    const int N = in_sizes[0] / IN_F;
    const int E = in_sizes[1] / 2;
    const int* src = edge_idx;
    const int* dst = edge_idx + E;

    const int nb1 = (N + 255) / 256;

    // ---- workspace layout ----
    char* wp = (char*)d_ws;
    int* row_ptr   = (int*)wp;            wp += ((size_t)N + 4) * sizeof(int);
    int* hist_cur  = (int*)wp;            wp += (size_t)N * sizeof(int);
    int* cursor    = (int*)wp;            wp += (size_t)N * sizeof(int);
    int* csr_src   = (int*)wp;            wp += (size_t)E * sizeof(int);
    int* blockSums = (int*)wp;            wp += 1024 * sizeof(int);
    float* dis     = (float*)wp;          wp += (size_t)N * sizeof(float);
    float* bufA    = (float*)wp;          wp += (size_t)N * 128 * sizeof(float);
    float* bufB    = (float*)wp;          wp += (size_t)N * 128 * sizeof(float);

    // ---- CSR build ----
    hipMemsetAsync(hist_cur, 0, (size_t)N * sizeof(int), stream);
    k_hist<<<(E + 255) / 256, 256, 0, stream>>>(dst, hist_cur, E);
    k_scan1<<<nb1, 256, 0, stream>>>(hist_cur, row_ptr, blockSums, N);
    k_scan2<<<1, 1024, 0, stream>>>(blockSums, nb1);
    k_scan3<<<nb1, 256, 0, stream>>>(row_ptr, blockSums, hist_cur, cursor, dis, N, E);
    k_fill<<<(E + 255) / 256, 256, 0, stream>>>(src, dst, cursor, csr_src, E);

    // ---- GNN layer 1 ----
    k_gemm_k128<128><<<(N + 31) / 32, 256, 0, stream>>>(x, gnn_W1, bufA, N);   // h1
    k_agg1<<<(N + 3) / 4, 256, 0, stream>>>(row_ptr, csr_src, dis, bufA, gnn_b1, bufB, N); // h

    // ---- GNN layer 2 (matmul) ----
    k_gemm_k128<64><<<(N + 31) / 32, 256, 0, stream>>>(bufB, gnn_W2, bufA, N); // h2 -> bufA

    // ---- MLP branch (bufB free now) ----
    k_mlp<<<(N + 31) / 32, 256, 0, stream>>>(x, mlp_W1, mlp_b1, mlp_W2, mlp_b2, bufB, N); // zmlp

    // ---- layer-2 aggregation fused with final mix ----
    k_agg2<<<(N + 3) / 4, 256, 0, stream>>>(row_ptr, csr_src, dis, bufA, gnn_b2, bufB, out, N);
}

// Round 4
// 662.958 us; speedup vs baseline: 10.4525x; 1.1674x over previous
//
#include <hip/hip_runtime.h>
#include <hip/hip_fp16.h>

static constexpr int IN_F  = 128;

// ================= CSR build =================

__global__ __launch_bounds__(256) void k_hist(const int* __restrict__ dst,
                                              int* __restrict__ hist, int E) {
    int i = blockIdx.x * 256 + threadIdx.x;
    if (i < E) atomicAdd(&hist[dst[i]], 1);
}

__global__ __launch_bounds__(256) void k_scan1(const int* __restrict__ hist,
                                               int* __restrict__ row_ptr,
                                               int* __restrict__ blockSums, int n) {
    __shared__ int s[256];
    int tid = threadIdx.x;
    int i   = blockIdx.x * 256 + tid;
    int v   = (i < n) ? hist[i] : 0;
    s[tid] = v;
    __syncthreads();
    int inc = v;
#pragma unroll
    for (int off = 1; off < 256; off <<= 1) {
        int add = (tid >= off) ? s[tid - off] : 0;
        __syncthreads();
        s[tid] = inc = inc + add;
        __syncthreads();
    }
    if (i < n) row_ptr[i] = inc - v;
    if (tid == 255) blockSums[blockIdx.x] = inc;
}

__global__ __launch_bounds__(1024) void k_scan2(int* __restrict__ blockSums, int nb) {
    __shared__ int s[1024];
    int tid = threadIdx.x;
    int v = (tid < nb) ? blockSums[tid] : 0;
    s[tid] = v;
    __syncthreads();
    int inc = v;
#pragma unroll
    for (int off = 1; off < 1024; off <<= 1) {
        int add = (tid >= off) ? s[tid - off] : 0;
        __syncthreads();
        s[tid] = inc = inc + add;
        __syncthreads();
    }
    if (tid < nb) blockSums[tid] = inc - v;
}

__global__ __launch_bounds__(256) void k_scan3(int* __restrict__ row_ptr,
                                               const int* __restrict__ blockSums,
                                               const int* __restrict__ hist,
                                               int* __restrict__ cursor,
                                               float* __restrict__ dis, int n, int E) {
    int i = blockIdx.x * 256 + threadIdx.x;
    if (i < n) {
        int rp = row_ptr[i] + blockSums[i >> 8];
        row_ptr[i] = rp;
        cursor[i]  = rp;
        dis[i] = rsqrtf(1.0f + (float)hist[i]);
    }
    if (i == 0) row_ptr[n] = E;
}

__global__ __launch_bounds__(256) void k_fill(const int* __restrict__ src,
                                              const int* __restrict__ dst,
                                              int* __restrict__ cursor,
                                              int* __restrict__ csr_src, int E) {
    int e = blockIdx.x * 256 + threadIdx.x;
    if (e < E) {
        int slot = atomicAdd(&cursor[dst[e]], 1);
        csr_src[slot] = src[e];
    }
}

// ================= gather-side GCN aggregation (fp16 tables) =================
// layer 1: h = relu(dis[d]*sum_j dis[s_j]*h1[s_j] + h1[d]/deg + b1), F=128, h1 fp16 -> h fp16
__global__ __launch_bounds__(256) void k_agg1(const int* __restrict__ rp,
                                              const int* __restrict__ csrc,
                                              const float* __restrict__ dis,
                                              const __half* __restrict__ h1,
                                              const float* __restrict__ b,
                                              __half* __restrict__ out, int n) {
    const int lane = threadIdx.x & 63;
    const int node = blockIdx.x * 4 + (threadIdx.x >> 6);
    if (node >= n) return;
    const int start = rp[node], end = rp[node + 1];
    float ax = 0.f, ay = 0.f;
    int j = start;
    for (; j + 1 < end; j += 2) {
        int s0 = csrc[j], s1 = csrc[j + 1];
        float w0 = dis[s0], w1 = dis[s1];
        __half2 v0 = *reinterpret_cast<const __half2*>(h1 + (size_t)s0 * 128 + lane * 2);
        __half2 v1 = *reinterpret_cast<const __half2*>(h1 + (size_t)s1 * 128 + lane * 2);
        float2 f0 = __half22float2(v0);
        float2 f1 = __half22float2(v1);
        ax += w0 * f0.x + w1 * f1.x;
        ay += w0 * f0.y + w1 * f1.y;
    }
    if (j < end) {
        int s0 = csrc[j];
        float w0 = dis[s0];
        float2 f0 = __half22float2(*reinterpret_cast<const __half2*>(h1 + (size_t)s0 * 128 + lane * 2));
        ax += w0 * f0.x;
        ay += w0 * f0.y;
    }
    const float dd = dis[node];
    const float di = 1.0f / (float)(end - start + 1);
    float2 hv = __half22float2(*reinterpret_cast<const __half2*>(h1 + (size_t)node * 128 + lane * 2));
    float2 bv = *reinterpret_cast<const float2*>(b + lane * 2);
    float ox = fmaxf(dd * ax + hv.x * di + bv.x, 0.f);
    float oy = fmaxf(dd * ay + hv.y * di + bv.y, 0.f);
    *reinterpret_cast<__half2*>(out + (size_t)node * 128 + lane * 2) = __floats2half2_rn(ox, oy);
}

// layer 2 + final fuse: out = 0.5*((dis[d]*sum + h2[d]/deg + b2) + zmlp), F=64, h2/zmlp fp16
__global__ __launch_bounds__(256) void k_agg2(const int* __restrict__ rp,
                                              const int* __restrict__ csrc,
                                              const float* __restrict__ dis,
                                              const __half* __restrict__ h2,
                                              const float* __restrict__ b,
                                              const __half* __restrict__ zmlp,
                                              float* __restrict__ out, int n) {
    const int lane = threadIdx.x & 63;
    const int node = blockIdx.x * 4 + (threadIdx.x >> 6);
    if (node >= n) return;
    const int start = rp[node], end = rp[node + 1];
    float acc = 0.f;
    int j = start;
    for (; j + 1 < end; j += 2) {
        int s0 = csrc[j], s1 = csrc[j + 1];
        acc += dis[s0] * __half2float(h2[(size_t)s0 * 64 + lane])
             + dis[s1] * __half2float(h2[(size_t)s1 * 64 + lane]);
    }
    if (j < end) {
        int s0 = csrc[j];
        acc += dis[s0] * __half2float(h2[(size_t)s0 * 64 + lane]);
    }
    const float dd = dis[node];
    const float di = 1.0f / (float)(end - start + 1);
    float hv = __half2float(h2[(size_t)node * 64 + lane]);
    float zg = dd * acc + hv * di + b[lane];
    out[(size_t)node * 64 + lane] = 0.5f * (zg + __half2float(zmlp[(size_t)node * 64 + lane]));
}

// helper: store float4 as 4 fp16
__device__ inline void store_h4(__half* p, float4 v) {
    __half2 p0 = __floats2half2_rn(v.x, v.y);
    __half2 p1 = __floats2half2_rn(v.z, v.w);
    union { __half2 h[2]; uint2 u; } pk;
    pk.h[0] = p0; pk.h[1] = p1;
    *reinterpret_cast<uint2*>(p) = pk.u;
}

// ================= fused: h1 = x@gnnW1 (fp16 out)  AND  zmlp = MLP(x) (fp16 out) =================
__global__ __launch_bounds__(256) void k_dual(const float* __restrict__ x,
                                              const float* __restrict__ gW1,
                                              const float* __restrict__ mW1,
                                              const float* __restrict__ mb1,
                                              const float* __restrict__ mW2,
                                              const float* __restrict__ mb2,
                                              __half* __restrict__ h1,
                                              __half* __restrict__ zmlp, int nrows) {
    __shared__ float As[32][128];
    __shared__ float Ms[32][128];
    const int tid  = threadIdx.x;
    const int row0 = blockIdx.x * 32;

#pragma unroll
    for (int i = 0; i < 4; ++i) {
        int slot = tid + i * 256;
        int r    = slot >> 5;
        int c4   = (slot & 31) * 4;
        float4 v = make_float4(0.f, 0.f, 0.f, 0.f);
        int gr = row0 + r;
        if (gr < nrows) v = *reinterpret_cast<const float4*>(x + (size_t)gr * 128 + c4);
        *reinterpret_cast<float4*>(&As[r][c4]) = v;
    }
    __syncthreads();

    const int cg4 = (tid & 31) * 4;
    const int r0  = (tid >> 5) * 4;

    // phase A: h1 = x @ gW1 -> fp16 global
    {
        float4 acc[4];
#pragma unroll
        for (int i = 0; i < 4; ++i) acc[i] = make_float4(0.f, 0.f, 0.f, 0.f);
#pragma unroll 4
        for (int k = 0; k < 128; k += 4) {
            const float4 w0 = *reinterpret_cast<const float4*>(gW1 + (k + 0) * 128 + cg4);
            const float4 w1 = *reinterpret_cast<const float4*>(gW1 + (k + 1) * 128 + cg4);
            const float4 w2 = *reinterpret_cast<const float4*>(gW1 + (k + 2) * 128 + cg4);
            const float4 w3 = *reinterpret_cast<const float4*>(gW1 + (k + 3) * 128 + cg4);
#pragma unroll
            for (int rr = 0; rr < 4; ++rr) {
                const float4 a = *reinterpret_cast<const float4*>(&As[r0 + rr][k]);
                acc[rr].x += a.x * w0.x + a.y * w1.x + a.z * w2.x + a.w * w3.x;
                acc[rr].y += a.x * w0.y + a.y * w1.y + a.z * w2.y + a.w * w3.y;
                acc[rr].z += a.x * w0.z + a.y * w1.z + a.z * w2.z + a.w * w3.z;
                acc[rr].w += a.x * w0.w + a.y * w1.w + a.z * w2.w + a.w * w3.w;
            }
        }
#pragma unroll
        for (int rr = 0; rr < 4; ++rr) {
            int gr = row0 + r0 + rr;
            if (gr < nrows) store_h4(h1 + (size_t)gr * 128 + cg4, acc[rr]);
        }
    }

    // phase B: Ms = relu(x @ mW1 + mb1)
    {
        float4 acc[4];
#pragma unroll
        for (int i = 0; i < 4; ++i) acc[i] = make_float4(0.f, 0.f, 0.f, 0.f);
#pragma unroll 4
        for (int k = 0; k < 128; k += 4) {
            const float4 w0 = *reinterpret_cast<const float4*>(mW1 + (k + 0) * 128 + cg4);
            const float4 w1 = *reinterpret_cast<const float4*>(mW1 + (k + 1) * 128 + cg4);
            const float4 w2 = *reinterpret_cast<const float4*>(mW1 + (k + 2) * 128 + cg4);
            const float4 w3 = *reinterpret_cast<const float4*>(mW1 + (k + 3) * 128 + cg4);
#pragma unroll
            for (int rr = 0; rr < 4; ++rr) {
                const float4 a = *reinterpret_cast<const float4*>(&As[r0 + rr][k]);
                acc[rr].x += a.x * w0.x + a.y * w1.x + a.z * w2.x + a.w * w3.x;
                acc[rr].y += a.x * w0.y + a.y * w1.y + a.z * w2.y + a.w * w3.y;
                acc[rr].z += a.x * w0.z + a.y * w1.z + a.z * w2.z + a.w * w3.z;
                acc[rr].w += a.x * w0.w + a.y * w1.w + a.z * w2.w + a.w * w3.w;
            }
        }
        const float4 bv = *reinterpret_cast<const float4*>(mb1 + cg4);
#pragma unroll
        for (int rr = 0; rr < 4; ++rr) {
            float4 o;
            o.x = fmaxf(acc[rr].x + bv.x, 0.f);
            o.y = fmaxf(acc[rr].y + bv.y, 0.f);
            o.z = fmaxf(acc[rr].z + bv.z, 0.f);
            o.w = fmaxf(acc[rr].w + bv.w, 0.f);
            *reinterpret_cast<float4*>(&Ms[r0 + rr][cg4]) = o;
        }
    }
    __syncthreads();

    // phase C: zmlp = Ms @ mW2 + mb2 -> fp16 global (F=64)
    {
        const int cg4b = (tid & 15) * 4;
        const int r0b  = (tid >> 4) * 2;
        float4 acc[2];
        acc[0] = make_float4(0.f, 0.f, 0.f, 0.f);
        acc[1] = make_float4(0.f, 0.f, 0.f, 0.f);
#pragma unroll 4
        for (int k = 0; k < 128; k += 4) {
            const float4 w0 = *reinterpret_cast<const float4*>(mW2 + (k + 0) * 64 + cg4b);
            const float4 w1 = *reinterpret_cast<const float4*>(mW2 + (k + 1) * 64 + cg4b);
            const float4 w2 = *reinterpret_cast<const float4*>(mW2 + (k + 2) * 64 + cg4b);
            const float4 w3 = *reinterpret_cast<const float4*>(mW2 + (k + 3) * 64 + cg4b);
#pragma unroll
            for (int rr = 0; rr < 2; ++rr) {
                const float4 a = *reinterpret_cast<const float4*>(&Ms[r0b + rr][k]);
                acc[rr].x += a.x * w0.x + a.y * w1.x + a.z * w2.x + a.w * w3.x;
                acc[rr].y += a.x * w0.y + a.y * w1.y + a.z * w2.y + a.w * w3.y;
                acc[rr].z += a.x * w0.z + a.y * w1.z + a.z * w2.z + a.w * w3.z;
                acc[rr].w += a.x * w0.w + a.y * w1.w + a.z * w2.w + a.w * w3.w;
            }
        }
        const float4 bv = *reinterpret_cast<const float4*>(mb2 + cg4b);
#pragma unroll
        for (int rr = 0; rr < 2; ++rr) {
            int gr = row0 + r0b + rr;
            if (gr < nrows) {
                float4 o;
                o.x = acc[rr].x + bv.x;
                o.y = acc[rr].y + bv.y;
                o.z = acc[rr].z + bv.z;
                o.w = acc[rr].w + bv.w;
                store_h4(zmlp + (size_t)gr * 64 + cg4b, o);
            }
        }
    }
}

// ================= gemm2: h2 = h @ gW2 (fp16 in, fp16 out), K=128, F=64 =================
__global__ __launch_bounds__(256) void k_gemm2(const __half* __restrict__ A,
                                               const float* __restrict__ W,
                                               __half* __restrict__ C, int nrows) {
    __shared__ float As[32][128];
    const int tid  = threadIdx.x;
    const int row0 = blockIdx.x * 32;

    // stage 32 rows x 128 fp16 -> f32 LDS. 512 uint4 slots (8 halves each), 2/thread
#pragma unroll
    for (int i = 0; i < 2; ++i) {
        int slot = tid + i * 256;      // 0..511
        int r    = slot >> 4;          // /16
        int c8   = (slot & 15) * 8;
        int gr = row0 + r;
        if (gr < nrows) {
            uint4 raw = *reinterpret_cast<const uint4*>(A + (size_t)gr * 128 + c8);
            const __half2* hp = reinterpret_cast<const __half2*>(&raw);
#pragma unroll
            for (int q = 0; q < 4; ++q) {
                float2 f = __half22float2(hp[q]);
                As[r][c8 + q * 2 + 0] = f.x;
                As[r][c8 + q * 2 + 1] = f.y;
            }
        } else {
#pragma unroll
            for (int q = 0; q < 8; ++q) As[r][c8 + q] = 0.f;
        }
    }
    __syncthreads();

    const int cg4 = (tid & 15) * 4;
    const int r0  = (tid >> 4) * 2;
    float4 acc[2];
    acc[0] = make_float4(0.f, 0.f, 0.f, 0.f);
    acc[1] = make_float4(0.f, 0.f, 0.f, 0.f);

#pragma unroll 4
    for (int k = 0; k < 128; k += 4) {
        const float4 w0 = *reinterpret_cast<const float4*>(W + (k + 0) * 64 + cg4);
        const float4 w1 = *reinterpret_cast<const float4*>(W + (k + 1) * 64 + cg4);
        const float4 w2 = *reinterpret_cast<const float4*>(W + (k + 2) * 64 + cg4);
        const float4 w3 = *reinterpret_cast<const float4*>(W + (k + 3) * 64 + cg4);
#pragma unroll
        for (int rr = 0; rr < 2; ++rr) {
            const float4 a = *reinterpret_cast<const float4*>(&As[r0 + rr][k]);
            acc[rr].x += a.x * w0.x + a.y * w1.x + a.z * w2.x + a.w * w3.x;
            acc[rr].y += a.x * w0.y + a.y * w1.y + a.z * w2.y + a.w * w3.y;
            acc[rr].z += a.x * w0.z + a.y * w1.z + a.z * w2.z + a.w * w3.z;
            acc[rr].w += a.x * w0.w + a.y * w1.w + a.z * w2.w + a.w * w3.w;
        }
    }

#pragma unroll
    for (int rr = 0; rr < 2; ++rr) {
        int gr = row0 + r0 + rr;
        if (gr < nrows) store_h4(C + (size_t)gr * 64 + cg4, acc[rr]);
    }
}

extern "C" void kernel_launch(void* const* d_in, const int* in_sizes, int n_in,
                              void* d_out, int out_size, void* d_ws, size_t ws_size,
                              hipStream_t stream) {
    const float* x      = (const float*)d_in[0];
    const int* edge_idx = (const int*)d_in[1];
    const float* gnn_W1 = (const float*)d_in[2];
    const float* gnn_b1 = (const float*)d_in[3];
    const float* gnn_W2 = (const float*)d_in[4];
    const float* gnn_b2 = (const float*)d_in[5];
    const float* mlp_W1 = (const float*)d_in[6];
    const float* mlp_b1 = (const float*)d_in[7];
    const float* mlp_W2 = (const float*)d_in[8];
    const float* mlp_b2 = (const float*)d_in[9];
    float* out = (float*)d_out;

    const int N = in_sizes[0] / IN_F;
    const int E = in_sizes[1] / 2;
    const int* src = edge_idx;
    const int* dst = edge_idx + E;

    const int nb1 = (N + 255) / 256;

    // ---- workspace layout ----
    char* wp = (char*)d_ws;
    int* row_ptr   = (int*)wp;            wp += ((size_t)N + 4) * sizeof(int);
    int* hist_cur  = (int*)wp;            wp += (size_t)N * sizeof(int);
    int* cursor    = (int*)wp;            wp += (size_t)N * sizeof(int);
    int* csr_src   = (int*)wp;            wp += (size_t)E * sizeof(int);
    int* blockSums = (int*)wp;            wp += 1024 * sizeof(int);
    float* dis     = (float*)wp;          wp += (size_t)N * sizeof(float);
    __half* h1     = (__half*)wp;         wp += (size_t)N * 128 * sizeof(__half);
    __half* hmid   = (__half*)wp;         wp += (size_t)N * 128 * sizeof(__half);
    __half* h2     = (__half*)wp;         wp += (size_t)N * 64 * sizeof(__half);
    __half* zmlp   = (__half*)wp;         wp += (size_t)N * 64 * sizeof(__half);

    // ---- CSR build ----
    hipMemsetAsync(hist_cur, 0, (size_t)N * sizeof(int), stream);
    k_hist<<<(E + 255) / 256, 256, 0, stream>>>(dst, hist_cur, E);
    k_scan1<<<nb1, 256, 0, stream>>>(hist_cur, row_ptr, blockSums, N);
    k_scan2<<<1, 1024, 0, stream>>>(blockSums, nb1);
    k_scan3<<<nb1, 256, 0, stream>>>(row_ptr, blockSums, hist_cur, cursor, dis, N, E);
    k_fill<<<(E + 255) / 256, 256, 0, stream>>>(src, dst, cursor, csr_src, E);

    // ---- fused gemm1 + MLP (reads x once) ----
    k_dual<<<(N + 31) / 32, 256, 0, stream>>>(x, gnn_W1, mlp_W1, mlp_b1, mlp_W2, mlp_b2,
                                              h1, zmlp, N);

    // ---- GNN layer 1 aggregation ----
    k_agg1<<<(N + 3) / 4, 256, 0, stream>>>(row_ptr, csr_src, dis, h1, gnn_b1, hmid, N);

    // ---- GNN layer 2 matmul ----
    k_gemm2<<<(N + 31) / 32, 256, 0, stream>>>(hmid, gnn_W2, h2, N);

    // ---- layer-2 aggregation fused with final mix ----
    k_agg2<<<(N + 3) / 4, 256, 0, stream>>>(row_ptr, csr_src, dis, h2, gnn_b2, zmlp, out, N);
}

// Round 5
// 435.518 us; speedup vs baseline: 15.9111x; 1.5222x over previous
//
#include <hip/hip_runtime.h>
#include <hip/hip_fp16.h>

static constexpr int IN_F = 128;

typedef _Float16 half8 __attribute__((ext_vector_type(8)));
typedef float f32x4 __attribute__((ext_vector_type(4)));

// ================= CSR build =================

__global__ __launch_bounds__(256) void k_hist(const int* __restrict__ dst,
                                              int* __restrict__ hist, int E) {
    int i = blockIdx.x * 256 + threadIdx.x;
    if (i < E) atomicAdd(&hist[dst[i]], 1);
}

__global__ __launch_bounds__(256) void k_scan1(const int* __restrict__ hist,
                                               int* __restrict__ row_ptr,
                                               int* __restrict__ blockSums, int n) {
    __shared__ int s[256];
    int tid = threadIdx.x;
    int i   = blockIdx.x * 256 + tid;
    int v   = (i < n) ? hist[i] : 0;
    s[tid] = v;
    __syncthreads();
    int inc = v;
#pragma unroll
    for (int off = 1; off < 256; off <<= 1) {
        int add = (tid >= off) ? s[tid - off] : 0;
        __syncthreads();
        s[tid] = inc = inc + add;
        __syncthreads();
    }
    if (i < n) row_ptr[i] = inc - v;
    if (tid == 255) blockSums[blockIdx.x] = inc;
}

__global__ __launch_bounds__(1024) void k_scan2(int* __restrict__ blockSums, int nb) {
    __shared__ int s[1024];
    int tid = threadIdx.x;
    int v = (tid < nb) ? blockSums[tid] : 0;
    s[tid] = v;
    __syncthreads();
    int inc = v;
#pragma unroll
    for (int off = 1; off < 1024; off <<= 1) {
        int add = (tid >= off) ? s[tid - off] : 0;
        __syncthreads();
        s[tid] = inc = inc + add;
        __syncthreads();
    }
    if (tid < nb) blockSums[tid] = inc - v;
}

__global__ __launch_bounds__(256) void k_scan3(int* __restrict__ row_ptr,
                                               const int* __restrict__ blockSums,
                                               const int* __restrict__ hist,
                                               int* __restrict__ cursor,
                                               float* __restrict__ dis, int n, int E) {
    int i = blockIdx.x * 256 + threadIdx.x;
    if (i < n) {
        int rp = row_ptr[i] + blockSums[i >> 8];
        row_ptr[i] = rp;
        cursor[i]  = rp;
        dis[i] = rsqrtf(1.0f + (float)hist[i]);
    }
    if (i == 0) row_ptr[n] = E;
}

__global__ __launch_bounds__(256) void k_fill(const int* __restrict__ src,
                                              const int* __restrict__ dst,
                                              int* __restrict__ cursor,
                                              int* __restrict__ csr_src, int E) {
    int e = blockIdx.x * 256 + threadIdx.x;
    if (e < E) {
        int slot = atomicAdd(&cursor[dst[e]], 1);
        csr_src[slot] = src[e];
    }
}

// ================= weight prep: f32 [K][F] -> fp16 [F][K] =================
__global__ __launch_bounds__(256) void k_prep_w(const float* __restrict__ gW1,
                                                const float* __restrict__ mW1,
                                                const float* __restrict__ mW2,
                                                const float* __restrict__ gW2,
                                                _Float16* __restrict__ tg1,
                                                _Float16* __restrict__ tm1,
                                                _Float16* __restrict__ tm2,
                                                _Float16* __restrict__ tg2) {
    int i = blockIdx.x * 256 + threadIdx.x;
    if (i < 16384)      { int j = i;         int f = j >> 7, k = j & 127; tg1[j] = (_Float16)gW1[k * 128 + f]; }
    else if (i < 32768) { int j = i - 16384; int f = j >> 7, k = j & 127; tm1[j] = (_Float16)mW1[k * 128 + f]; }
    else if (i < 40960) { int j = i - 32768; int f = j >> 7, k = j & 127; tm2[j] = (_Float16)mW2[k * 64 + f]; }
    else if (i < 49152) { int j = i - 40960; int f = j >> 7, k = j & 127; tg2[j] = (_Float16)gW2[k * 64 + f]; }
}

// ============ MFMA GEMM: C[n x F] fp16 = A[n x 128] @ W[128 x F] ============
// 64 rows/block, 4 waves (wave w = rows 16w..16w+15). LDS 16B-slot XOR swizzle.
template <int F, typename TA>
__global__ __launch_bounds__(256) void k_mm(const TA* __restrict__ A,
                                            const _Float16* __restrict__ Wt,  // [F][128]
                                            _Float16* __restrict__ C, int nrows) {
    __shared__ _Float16 As[64 * 128];
    __shared__ _Float16 Ws[F * 128];
    const int tid  = threadIdx.x;
    const int row0 = blockIdx.x * 64;

    // stage A (64 rows x 128 k), convert f32->fp16 if needed
#pragma unroll
    for (int p = 0; p < 4; ++p) {
        int sid = p * 256 + tid;           // 0..1023
        int r = sid >> 4, s = sid & 15;
        int gr = row0 + r;
        uint4 v = make_uint4(0, 0, 0, 0);
        if (gr < nrows) {
            if constexpr (sizeof(TA) == 4) {
                const float4 f0 = *reinterpret_cast<const float4*>(A + (size_t)gr * 128 + s * 8);
                const float4 f1 = *reinterpret_cast<const float4*>(A + (size_t)gr * 128 + s * 8 + 4);
                _Float16 t[8] = {(_Float16)f0.x, (_Float16)f0.y, (_Float16)f0.z, (_Float16)f0.w,
                                 (_Float16)f1.x, (_Float16)f1.y, (_Float16)f1.z, (_Float16)f1.w};
                v = *reinterpret_cast<uint4*>(t);
            } else {
                v = *reinterpret_cast<const uint4*>(A + (size_t)gr * 128 + s * 8);
            }
        }
        *reinterpret_cast<uint4*>(&As[r * 128 + ((s ^ (r & 7)) * 8)]) = v;
    }
    // stage W (F rows x 128 k)
#pragma unroll
    for (int p = 0; p < F / 16; ++p) {
        int sid = p * 256 + tid;
        int r = sid >> 4, s = sid & 15;
        uint4 v = *reinterpret_cast<const uint4*>(Wt + (size_t)r * 128 + s * 8);
        *reinterpret_cast<uint4*>(&Ws[r * 128 + ((s ^ (r & 7)) * 8)]) = v;
    }
    __syncthreads();

    const int lane = tid & 63;
    const int wv   = tid >> 6;
    const int mrow = wv * 16 + (lane & 15);
    const int kg   = lane >> 4;          // 0..3

    half8 a[4];
#pragma unroll
    for (int kk = 0; kk < 4; ++kk)
        a[kk] = *reinterpret_cast<const half8*>(&As[mrow * 128 + (((kk * 4 + kg) ^ (mrow & 7)) * 8)]);

#pragma unroll
    for (int ct = 0; ct < F / 16; ++ct) {
        const int ncol = ct * 16 + (lane & 15);
        f32x4 acc = {0.f, 0.f, 0.f, 0.f};
#pragma unroll
        for (int kk = 0; kk < 4; ++kk) {
            half8 b = *reinterpret_cast<const half8*>(&Ws[ncol * 128 + (((kk * 4 + kg) ^ (ncol & 7)) * 8)]);
            acc = __builtin_amdgcn_mfma_f32_16x16x32_f16(a[kk], b, acc, 0, 0, 0);
        }
        const int grow = row0 + wv * 16 + kg * 4;
#pragma unroll
        for (int j = 0; j < 4; ++j)
            if (grow + j < nrows)
                C[(size_t)(grow + j) * F + ncol] = (_Float16)acc[j];
    }
}

// ============ fused MFMA MLP: z = relu(x@W1 + b1) @ W2 + b2, fp16 out ============
__global__ __launch_bounds__(256) void k_mlp_mfma(const float* __restrict__ x,
                                                  const _Float16* __restrict__ tW1,  // [128][128]
                                                  const _Float16* __restrict__ tW2,  // [64][128]
                                                  const float* __restrict__ b1,
                                                  const float* __restrict__ b2,
                                                  _Float16* __restrict__ z, int nrows) {
    __shared__ _Float16 As[64 * 128];
    __shared__ _Float16 W1s[128 * 128];
    __shared__ _Float16 W2s[64 * 128];
    __shared__ _Float16 Ms[64 * 128];
    const int tid  = threadIdx.x;
    const int row0 = blockIdx.x * 64;

#pragma unroll
    for (int p = 0; p < 4; ++p) {
        int sid = p * 256 + tid;
        int r = sid >> 4, s = sid & 15;
        int gr = row0 + r;
        uint4 v = make_uint4(0, 0, 0, 0);
        if (gr < nrows) {
            const float4 f0 = *reinterpret_cast<const float4*>(x + (size_t)gr * 128 + s * 8);
            const float4 f1 = *reinterpret_cast<const float4*>(x + (size_t)gr * 128 + s * 8 + 4);
            _Float16 t[8] = {(_Float16)f0.x, (_Float16)f0.y, (_Float16)f0.z, (_Float16)f0.w,
                             (_Float16)f1.x, (_Float16)f1.y, (_Float16)f1.z, (_Float16)f1.w};
            v = *reinterpret_cast<uint4*>(t);
        }
        *reinterpret_cast<uint4*>(&As[r * 128 + ((s ^ (r & 7)) * 8)]) = v;
    }
#pragma unroll
    for (int p = 0; p < 8; ++p) {
        int sid = p * 256 + tid;
        int r = sid >> 4, s = sid & 15;
        uint4 v = *reinterpret_cast<const uint4*>(tW1 + (size_t)r * 128 + s * 8);
        *reinterpret_cast<uint4*>(&W1s[r * 128 + ((s ^ (r & 7)) * 8)]) = v;
    }
#pragma unroll
    for (int p = 0; p < 4; ++p) {
        int sid = p * 256 + tid;
        int r = sid >> 4, s = sid & 15;
        uint4 v = *reinterpret_cast<const uint4*>(tW2 + (size_t)r * 128 + s * 8);
        *reinterpret_cast<uint4*>(&W2s[r * 128 + ((s ^ (r & 7)) * 8)]) = v;
    }
    __syncthreads();

    const int lane = tid & 63;
    const int wv   = tid >> 6;
    const int mrow = wv * 16 + (lane & 15);
    const int kg   = lane >> 4;

    half8 a[4];
#pragma unroll
    for (int kk = 0; kk < 4; ++kk)
        a[kk] = *reinterpret_cast<const half8*>(&As[mrow * 128 + (((kk * 4 + kg) ^ (mrow & 7)) * 8)]);

    // phase B: M = relu(x@W1 + b1) -> Ms (swizzled, fp16)
#pragma unroll
    for (int ct = 0; ct < 8; ++ct) {
        const int ncol = ct * 16 + (lane & 15);
        f32x4 acc = {0.f, 0.f, 0.f, 0.f};
#pragma unroll
        for (int kk = 0; kk < 4; ++kk) {
            half8 b = *reinterpret_cast<const half8*>(&W1s[ncol * 128 + (((kk * 4 + kg) ^ (ncol & 7)) * 8)]);
            acc = __builtin_amdgcn_mfma_f32_16x16x32_f16(a[kk], b, acc, 0, 0, 0);
        }
        const float bias = b1[ncol];
#pragma unroll
        for (int j = 0; j < 4; ++j) {
            int r = wv * 16 + kg * 4 + j;
            float v = fmaxf((float)acc[j] + bias, 0.f);
            Ms[r * 128 + (((ncol >> 3) ^ (r & 7)) * 8) + (ncol & 7)] = (_Float16)v;
        }
    }
    __syncthreads();

    // phase C: z = M @ W2 + b2 (F=64)
    half8 am[4];
#pragma unroll
    for (int kk = 0; kk < 4; ++kk)
        am[kk] = *reinterpret_cast<const half8*>(&Ms[mrow * 128 + (((kk * 4 + kg) ^ (mrow & 7)) * 8)]);

#pragma unroll
    for (int ct = 0; ct < 4; ++ct) {
        const int ncol = ct * 16 + (lane & 15);
        f32x4 acc = {0.f, 0.f, 0.f, 0.f};
#pragma unroll
        for (int kk = 0; kk < 4; ++kk) {
            half8 b = *reinterpret_cast<const half8*>(&W2s[ncol * 128 + (((kk * 4 + kg) ^ (ncol & 7)) * 8)]);
            acc = __builtin_amdgcn_mfma_f32_16x16x32_f16(am[kk], b, acc, 0, 0, 0);
        }
        const float bias = b2[ncol];
        const int grow = row0 + wv * 16 + kg * 4;
#pragma unroll
        for (int j = 0; j < 4; ++j)
            if (grow + j < nrows)
                z[(size_t)(grow + j) * 64 + ncol] = (_Float16)((float)acc[j] + bias);
    }
}

// ================= gather-side GCN aggregation (fp16 tables) =================
__global__ __launch_bounds__(256) void k_agg1(const int* __restrict__ rp,
                                              const int* __restrict__ csrc,
                                              const float* __restrict__ dis,
                                              const __half* __restrict__ h1,
                                              const float* __restrict__ b,
                                              __half* __restrict__ out, int n) {
    const int lane = threadIdx.x & 63;
    const int node = blockIdx.x * 4 + (threadIdx.x >> 6);
    if (node >= n) return;
    const int start = rp[node], end = rp[node + 1];
    float ax = 0.f, ay = 0.f;
    int j = start;
    for (; j + 3 < end; j += 4) {
        int s0 = csrc[j], s1 = csrc[j + 1], s2 = csrc[j + 2], s3 = csrc[j + 3];
        float w0 = dis[s0], w1 = dis[s1], w2 = dis[s2], w3 = dis[s3];
        float2 f0 = __half22float2(*reinterpret_cast<const __half2*>(h1 + (size_t)s0 * 128 + lane * 2));
        float2 f1 = __half22float2(*reinterpret_cast<const __half2*>(h1 + (size_t)s1 * 128 + lane * 2));
        float2 f2 = __half22float2(*reinterpret_cast<const __half2*>(h1 + (size_t)s2 * 128 + lane * 2));
        float2 f3 = __half22float2(*reinterpret_cast<const __half2*>(h1 + (size_t)s3 * 128 + lane * 2));
        ax += w0 * f0.x + w1 * f1.x + w2 * f2.x + w3 * f3.x;
        ay += w0 * f0.y + w1 * f1.y + w2 * f2.y + w3 * f3.y;
    }
    for (; j < end; ++j) {
        int s0 = csrc[j];
        float w0 = dis[s0];
        float2 f0 = __half22float2(*reinterpret_cast<const __half2*>(h1 + (size_t)s0 * 128 + lane * 2));
        ax += w0 * f0.x;
        ay += w0 * f0.y;
    }
    const float dd = dis[node];
    const float di = 1.0f / (float)(end - start + 1);
    float2 hv = __half22float2(*reinterpret_cast<const __half2*>(h1 + (size_t)node * 128 + lane * 2));
    float2 bv = *reinterpret_cast<const float2*>(b + lane * 2);
    float ox = fmaxf(dd * ax + hv.x * di + bv.x, 0.f);
    float oy = fmaxf(dd * ay + hv.y * di + bv.y, 0.f);
    *reinterpret_cast<__half2*>(out + (size_t)node * 128 + lane * 2) = __floats2half2_rn(ox, oy);
}

__global__ __launch_bounds__(256) void k_agg2(const int* __restrict__ rp,
                                              const int* __restrict__ csrc,
                                              const float* __restrict__ dis,
                                              const __half* __restrict__ h2,
                                              const float* __restrict__ b,
                                              const __half* __restrict__ zmlp,
                                              float* __restrict__ out, int n) {
    const int lane = threadIdx.x & 63;
    const int node = blockIdx.x * 4 + (threadIdx.x >> 6);
    if (node >= n) return;
    const int start = rp[node], end = rp[node + 1];
    float acc = 0.f;
    int j = start;
    for (; j + 3 < end; j += 4) {
        int s0 = csrc[j], s1 = csrc[j + 1], s2 = csrc[j + 2], s3 = csrc[j + 3];
        acc += dis[s0] * __half2float(h2[(size_t)s0 * 64 + lane])
             + dis[s1] * __half2float(h2[(size_t)s1 * 64 + lane])
             + dis[s2] * __half2float(h2[(size_t)s2 * 64 + lane])
             + dis[s3] * __half2float(h2[(size_t)s3 * 64 + lane]);
    }
    for (; j < end; ++j) {
        int s0 = csrc[j];
        acc += dis[s0] * __half2float(h2[(size_t)s0 * 64 + lane]);
    }
    const float dd = dis[node];
    const float di = 1.0f / (float)(end - start + 1);
    float hv = __half2float(h2[(size_t)node * 64 + lane]);
    float zg = dd * acc + hv * di + b[lane];
    out[(size_t)node * 64 + lane] = 0.5f * (zg + __half2float(zmlp[(size_t)node * 64 + lane]));
}

extern "C" void kernel_launch(void* const* d_in, const int* in_sizes, int n_in,
                              void* d_out, int out_size, void* d_ws, size_t ws_size,
                              hipStream_t stream) {
    const float* x      = (const float*)d_in[0];
    const int* edge_idx = (const int*)d_in[1];
    const float* gnn_W1 = (const float*)d_in[2];
    const float* gnn_b1 = (const float*)d_in[3];
    const float* gnn_W2 = (const float*)d_in[4];
    const float* gnn_b2 = (const float*)d_in[5];
    const float* mlp_W1 = (const float*)d_in[6];
    const float* mlp_b1 = (const float*)d_in[7];
    const float* mlp_W2 = (const float*)d_in[8];
    const float* mlp_b2 = (const float*)d_in[9];
    float* out = (float*)d_out;

    const int N = in_sizes[0] / IN_F;
    const int E = in_sizes[1] / 2;
    const int* src = edge_idx;
    const int* dst = edge_idx + E;

    const int nb1 = (N + 255) / 256;

    // ---- workspace layout ----
    char* wp = (char*)d_ws;
    int* row_ptr   = (int*)wp;            wp += ((size_t)N + 4) * sizeof(int);
    int* hist_cur  = (int*)wp;            wp += (size_t)N * sizeof(int);
    int* cursor    = (int*)wp;            wp += (size_t)N * sizeof(int);
    int* csr_src   = (int*)wp;            wp += (size_t)E * sizeof(int);
    int* blockSums = (int*)wp;            wp += 1024 * sizeof(int);
    float* dis     = (float*)wp;          wp += (size_t)N * sizeof(float);
    _Float16* tg1  = (_Float16*)wp;       wp += 16384 * sizeof(_Float16);
    _Float16* tm1  = (_Float16*)wp;       wp += 16384 * sizeof(_Float16);
    _Float16* tm2  = (_Float16*)wp;       wp += 8192 * sizeof(_Float16);
    _Float16* tg2  = (_Float16*)wp;       wp += 8192 * sizeof(_Float16);
    _Float16* h1   = (_Float16*)wp;       wp += (size_t)N * 128 * sizeof(_Float16);
    _Float16* hmid = (_Float16*)wp;       wp += (size_t)N * 128 * sizeof(_Float16);
    _Float16* h2   = (_Float16*)wp;       wp += (size_t)N * 64 * sizeof(_Float16);
    _Float16* zmlp = (_Float16*)wp;       wp += (size_t)N * 64 * sizeof(_Float16);

    // ---- weight prep + CSR build ----
    k_prep_w<<<192, 256, 0, stream>>>(gnn_W1, mlp_W1, mlp_W2, gnn_W2, tg1, tm1, tm2, tg2);
    hipMemsetAsync(hist_cur, 0, (size_t)N * sizeof(int), stream);
    k_hist<<<(E + 255) / 256, 256, 0, stream>>>(dst, hist_cur, E);
    k_scan1<<<nb1, 256, 0, stream>>>(hist_cur, row_ptr, blockSums, N);
    k_scan2<<<1, 1024, 0, stream>>>(blockSums, nb1);
    k_scan3<<<nb1, 256, 0, stream>>>(row_ptr, blockSums, hist_cur, cursor, dis, N, E);
    k_fill<<<(E + 255) / 256, 256, 0, stream>>>(src, dst, cursor, csr_src, E);

    const int gblocks = (N + 63) / 64;

    // ---- h1 = x @ gW1 (MFMA) ----
    k_mm<128, float><<<gblocks, 256, 0, stream>>>(x, tg1, h1, N);

    // ---- MLP branch (MFMA, fused) ----
    k_mlp_mfma<<<gblocks, 256, 0, stream>>>(x, tm1, tm2, mlp_b1, mlp_b2, zmlp, N);

    // ---- GNN layer 1 aggregation ----
    k_agg1<<<(N + 3) / 4, 256, 0, stream>>>(row_ptr, csr_src, dis, (const __half*)h1, gnn_b1,
                                            (__half*)hmid, N);

    // ---- h2 = hmid @ gW2 (MFMA) ----
    k_mm<64, _Float16><<<gblocks, 256, 0, stream>>>(hmid, tg2, h2, N);

    // ---- layer-2 aggregation fused with final mix ----
    k_agg2<<<(N + 3) / 4, 256, 0, stream>>>(row_ptr, csr_src, dis, (const __half*)h2, gnn_b2,
                                            (const __half*)zmlp, out, N);
}

// Round 6
// 385.562 us; speedup vs baseline: 17.9726x; 1.1296x over previous
//
#include <hip/hip_runtime.h>
#include <hip/hip_fp16.h>

static constexpr int IN_F = 128;
static constexpr int CPB  = 128;   // chunks (blocks) per bucket for histb/fill

typedef _Float16 half8 __attribute__((ext_vector_type(8)));
typedef float f32x4 __attribute__((ext_vector_type(4)));

// ================= bucketed CSR build =================
// bucket b = dst >> 11  (2048 nodes/bucket, NB = ceil(N/2048) <= 64 for N <= 131072)
// record  = (dstLow:11 << 17) | src:17   (src < 2^17)

__global__ __launch_bounds__(1024) void kb_count(const int* __restrict__ dst,
                                                 int* __restrict__ bcount, int E) {
    __shared__ int cnt[64];
    const int tid = threadIdx.x;
    if (tid < 64) cnt[tid] = 0;
    __syncthreads();
#pragma unroll
    for (int q = 0; q < 4; ++q) {
        int i = blockIdx.x * 4096 + q * 1024 + tid;
        if (i < E) atomicAdd(&cnt[dst[i] >> 11], 1);
    }
    __syncthreads();
    if (tid < 64 && cnt[tid] > 0) atomicAdd(&bcount[tid], cnt[tid]);
}

__global__ __launch_bounds__(64) void k_scanb(const int* __restrict__ bcount,
                                              int* __restrict__ bbase,
                                              int* __restrict__ bcursor, int NB) {
    __shared__ int s[64];
    const int tid = threadIdx.x;
    int v = (tid < NB) ? bcount[tid] : 0;
    s[tid] = v;
    __syncthreads();
    int inc = v;
#pragma unroll
    for (int off = 1; off < 64; off <<= 1) {
        int add = (tid >= off) ? s[tid - off] : 0;
        __syncthreads();
        s[tid] = inc = inc + add;
        __syncthreads();
    }
    if (tid < NB) { bbase[tid] = inc - v; bcursor[tid] = inc - v; }
    if (tid == NB - 1) bbase[NB] = inc;   // total = E
}

__global__ __launch_bounds__(1024) void kb_move(const int* __restrict__ src,
                                                const int* __restrict__ dst,
                                                int* __restrict__ bcursor,
                                                unsigned* __restrict__ recs, int E) {
    __shared__ int cnt[64];
    __shared__ int off[64];
    const int tid = threadIdx.x;
    if (tid < 64) cnt[tid] = 0;
    __syncthreads();

    int bq[4];
    unsigned rq[4];
#pragma unroll
    for (int q = 0; q < 4; ++q) {
        int i = blockIdx.x * 4096 + q * 1024 + tid;
        if (i < E) {
            int d = dst[i];
            int s = src[i];
            bq[q] = d >> 11;
            rq[q] = (unsigned)(((d & 2047) << 17) | s);
            atomicAdd(&cnt[bq[q]], 1);
        } else {
            bq[q] = -1;
            rq[q] = 0u;
        }
    }
    __syncthreads();
    if (tid < 64 && cnt[tid] > 0) off[tid] = atomicAdd(&bcursor[tid], cnt[tid]);
    __syncthreads();
#pragma unroll
    for (int q = 0; q < 4; ++q) {
        if (bq[q] >= 0) {
            int p = atomicAdd(&off[bq[q]], 1);
            recs[p] = rq[q];
        }
    }
}

__global__ __launch_bounds__(256) void k_histb(const unsigned* __restrict__ recs,
                                               const int* __restrict__ bbase,
                                               int* __restrict__ hist) {
    const int b = blockIdx.x / CPB;
    const int c = blockIdx.x % CPB;
    const int s = bbase[b], e = bbase[b + 1];
    const int nbase = b << 11;
    for (int i = s + c * 256 + threadIdx.x; i < e; i += CPB * 256)
        atomicAdd(&hist[nbase + (int)(recs[i] >> 17)], 1);
}

__global__ __launch_bounds__(256) void kb_fill(const unsigned* __restrict__ recs,
                                               const int* __restrict__ bbase,
                                               int* __restrict__ cursor,
                                               int* __restrict__ csr_src) {
    const int b = blockIdx.x / CPB;
    const int c = blockIdx.x % CPB;
    const int s = bbase[b], e = bbase[b + 1];
    const int nbase = b << 11;
    for (int i = s + c * 256 + threadIdx.x; i < e; i += CPB * 256) {
        unsigned r = recs[i];
        int d = nbase + (int)(r >> 17);
        int slot = atomicAdd(&cursor[d], 1);
        csr_src[slot] = (int)(r & 0x1FFFFu);
    }
}

// ================= scans over N (unchanged) =================
__global__ __launch_bounds__(256) void k_scan1(const int* __restrict__ hist,
                                               int* __restrict__ row_ptr,
                                               int* __restrict__ blockSums, int n) {
    __shared__ int s[256];
    int tid = threadIdx.x;
    int i   = blockIdx.x * 256 + tid;
    int v   = (i < n) ? hist[i] : 0;
    s[tid] = v;
    __syncthreads();
    int inc = v;
#pragma unroll
    for (int off = 1; off < 256; off <<= 1) {
        int add = (tid >= off) ? s[tid - off] : 0;
        __syncthreads();
        s[tid] = inc = inc + add;
        __syncthreads();
    }
    if (i < n) row_ptr[i] = inc - v;
    if (tid == 255) blockSums[blockIdx.x] = inc;
}

__global__ __launch_bounds__(1024) void k_scan2(int* __restrict__ blockSums, int nb) {
    __shared__ int s[1024];
    int tid = threadIdx.x;
    int v = (tid < nb) ? blockSums[tid] : 0;
    s[tid] = v;
    __syncthreads();
    int inc = v;
#pragma unroll
    for (int off = 1; off < 1024; off <<= 1) {
        int add = (tid >= off) ? s[tid - off] : 0;
        __syncthreads();
        s[tid] = inc = inc + add;
        __syncthreads();
    }
    if (tid < nb) blockSums[tid] = inc - v;
}

__global__ __launch_bounds__(256) void k_scan3(int* __restrict__ row_ptr,
                                               const int* __restrict__ blockSums,
                                               const int* __restrict__ hist,
                                               int* __restrict__ cursor,
                                               float* __restrict__ dis, int n, int E) {
    int i = blockIdx.x * 256 + threadIdx.x;
    if (i < n) {
        int rp = row_ptr[i] + blockSums[i >> 8];
        row_ptr[i] = rp;
        cursor[i]  = rp;
        dis[i] = rsqrtf(1.0f + (float)hist[i]);
    }
    if (i == 0) row_ptr[n] = E;
}

// ================= weight prep: f32 [K][F] -> fp16 [F][K] =================
__global__ __launch_bounds__(256) void k_prep_w(const float* __restrict__ gW1,
                                                const float* __restrict__ mW1,
                                                const float* __restrict__ mW2,
                                                const float* __restrict__ gW2,
                                                _Float16* __restrict__ tg1,
                                                _Float16* __restrict__ tm1,
                                                _Float16* __restrict__ tm2,
                                                _Float16* __restrict__ tg2) {
    int i = blockIdx.x * 256 + threadIdx.x;
    if (i < 16384)      { int j = i;         int f = j >> 7, k = j & 127; tg1[j] = (_Float16)gW1[k * 128 + f]; }
    else if (i < 32768) { int j = i - 16384; int f = j >> 7, k = j & 127; tm1[j] = (_Float16)mW1[k * 128 + f]; }
    else if (i < 40960) { int j = i - 32768; int f = j >> 7, k = j & 127; tm2[j] = (_Float16)mW2[k * 64 + f]; }
    else if (i < 49152) { int j = i - 40960; int f = j >> 7, k = j & 127; tg2[j] = (_Float16)gW2[k * 64 + f]; }
}

// ============ fused MFMA: h1 = x@gW1, z = relu(x@mW1+b1)@mW2+b2 ============
// 64 rows/block, 4 waves. One x tile staged once; W buffer re-staged per phase.
__global__ __launch_bounds__(256) void k_dual_mfma(const float* __restrict__ x,
                                                   const _Float16* __restrict__ tg1,
                                                   const _Float16* __restrict__ tm1,
                                                   const _Float16* __restrict__ tm2,
                                                   const float* __restrict__ b1,
                                                   const float* __restrict__ b2,
                                                   _Float16* __restrict__ h1,
                                                   _Float16* __restrict__ z, int nrows) {
    __shared__ _Float16 As[64 * 128];    // 16 KB
    __shared__ _Float16 Ws[128 * 128];   // 32 KB
    __shared__ _Float16 Ms[64 * 128];    // 16 KB
    const int tid  = threadIdx.x;
    const int row0 = blockIdx.x * 64;

    // stage A (convert f32->fp16, 16B-slot XOR swizzle)
#pragma unroll
    for (int p = 0; p < 4; ++p) {
        int sid = p * 256 + tid;
        int r = sid >> 4, s = sid & 15;
        int gr = row0 + r;
        uint4 v = make_uint4(0, 0, 0, 0);
        if (gr < nrows) {
            const float4 f0 = *reinterpret_cast<const float4*>(x + (size_t)gr * 128 + s * 8);
            const float4 f1 = *reinterpret_cast<const float4*>(x + (size_t)gr * 128 + s * 8 + 4);
            _Float16 t[8] = {(_Float16)f0.x, (_Float16)f0.y, (_Float16)f0.z, (_Float16)f0.w,
                             (_Float16)f1.x, (_Float16)f1.y, (_Float16)f1.z, (_Float16)f1.w};
            v = *reinterpret_cast<uint4*>(t);
        }
        *reinterpret_cast<uint4*>(&As[r * 128 + ((s ^ (r & 7)) * 8)]) = v;
    }
    // stage Ws = tg1 (128 rows)
#pragma unroll
    for (int p = 0; p < 8; ++p) {
        int sid = p * 256 + tid;
        int r = sid >> 4, s = sid & 15;
        uint4 v = *reinterpret_cast<const uint4*>(tg1 + (size_t)r * 128 + s * 8);
        *reinterpret_cast<uint4*>(&Ws[r * 128 + ((s ^ (r & 7)) * 8)]) = v;
    }
    __syncthreads();

    const int lane = tid & 63;
    const int wv   = tid >> 6;
    const int mrow = wv * 16 + (lane & 15);
    const int kg   = lane >> 4;

    half8 a[4];
#pragma unroll
    for (int kk = 0; kk < 4; ++kk)
        a[kk] = *reinterpret_cast<const half8*>(&As[mrow * 128 + (((kk * 4 + kg) ^ (mrow & 7)) * 8)]);

    // phase 1: h1 = x @ gW1
#pragma unroll
    for (int ct = 0; ct < 8; ++ct) {
        const int ncol = ct * 16 + (lane & 15);
        f32x4 acc = {0.f, 0.f, 0.f, 0.f};
#pragma unroll
        for (int kk = 0; kk < 4; ++kk) {
            half8 b = *reinterpret_cast<const half8*>(&Ws[ncol * 128 + (((kk * 4 + kg) ^ (ncol & 7)) * 8)]);
            acc = __builtin_amdgcn_mfma_f32_16x16x32_f16(a[kk], b, acc, 0, 0, 0);
        }
        const int grow = row0 + wv * 16 + kg * 4;
#pragma unroll
        for (int j = 0; j < 4; ++j)
            if (grow + j < nrows)
                h1[(size_t)(grow + j) * 128 + ncol] = (_Float16)acc[j];
    }
    __syncthreads();

    // restage Ws = tm1
#pragma unroll
    for (int p = 0; p < 8; ++p) {
        int sid = p * 256 + tid;
        int r = sid >> 4, s = sid & 15;
        uint4 v = *reinterpret_cast<const uint4*>(tm1 + (size_t)r * 128 + s * 8);
        *reinterpret_cast<uint4*>(&Ws[r * 128 + ((s ^ (r & 7)) * 8)]) = v;
    }
    __syncthreads();

    // phase 2: M = relu(x@mW1 + b1) -> Ms (swizzled fp16)
#pragma unroll
    for (int ct = 0; ct < 8; ++ct) {
        const int ncol = ct * 16 + (lane & 15);
        f32x4 acc = {0.f, 0.f, 0.f, 0.f};
#pragma unroll
        for (int kk = 0; kk < 4; ++kk) {
            half8 b = *reinterpret_cast<const half8*>(&Ws[ncol * 128 + (((kk * 4 + kg) ^ (ncol & 7)) * 8)]);
            acc = __builtin_amdgcn_mfma_f32_16x16x32_f16(a[kk], b, acc, 0, 0, 0);
        }
        const float bias = b1[ncol];
#pragma unroll
        for (int j = 0; j < 4; ++j) {
            int r = wv * 16 + kg * 4 + j;
            float v = fmaxf((float)acc[j] + bias, 0.f);
            Ms[r * 128 + (((ncol >> 3) ^ (r & 7)) * 8) + (ncol & 7)] = (_Float16)v;
        }
    }
    __syncthreads();

    // restage Ws[0:64] = tm2
#pragma unroll
    for (int p = 0; p < 4; ++p) {
        int sid = p * 256 + tid;
        int r = sid >> 4, s = sid & 15;
        uint4 v = *reinterpret_cast<const uint4*>(tm2 + (size_t)r * 128 + s * 8);
        *reinterpret_cast<uint4*>(&Ws[r * 128 + ((s ^ (r & 7)) * 8)]) = v;
    }
    __syncthreads();

    // phase 3: z = M @ mW2 + b2 (F=64)
    half8 am[4];
#pragma unroll
    for (int kk = 0; kk < 4; ++kk)
        am[kk] = *reinterpret_cast<const half8*>(&Ms[mrow * 128 + (((kk * 4 + kg) ^ (mrow & 7)) * 8)]);

#pragma unroll
    for (int ct = 0; ct < 4; ++ct) {
        const int ncol = ct * 16 + (lane & 15);
        f32x4 acc = {0.f, 0.f, 0.f, 0.f};
#pragma unroll
        for (int kk = 0; kk < 4; ++kk) {
            half8 b = *reinterpret_cast<const half8*>(&Ws[ncol * 128 + (((kk * 4 + kg) ^ (ncol & 7)) * 8)]);
            acc = __builtin_amdgcn_mfma_f32_16x16x32_f16(am[kk], b, acc, 0, 0, 0);
        }
        const float bias = b2[ncol];
        const int grow = row0 + wv * 16 + kg * 4;
#pragma unroll
        for (int j = 0; j < 4; ++j)
            if (grow + j < nrows)
                z[(size_t)(grow + j) * 64 + ncol] = (_Float16)((float)acc[j] + bias);
    }
}

// ============ MFMA GEMM: h2 = hmid @ gW2 (fp16 in/out), F=64 ============
__global__ __launch_bounds__(256) void k_mm64(const _Float16* __restrict__ A,
                                              const _Float16* __restrict__ Wt,  // [64][128]
                                              _Float16* __restrict__ C, int nrows) {
    __shared__ _Float16 As[64 * 128];
    __shared__ _Float16 Ws[64 * 128];
    const int tid  = threadIdx.x;
    const int row0 = blockIdx.x * 64;

#pragma unroll
    for (int p = 0; p < 4; ++p) {
        int sid = p * 256 + tid;
        int r = sid >> 4, s = sid & 15;
        int gr = row0 + r;
        uint4 v = make_uint4(0, 0, 0, 0);
        if (gr < nrows) v = *reinterpret_cast<const uint4*>(A + (size_t)gr * 128 + s * 8);
        *reinterpret_cast<uint4*>(&As[r * 128 + ((s ^ (r & 7)) * 8)]) = v;
    }
#pragma unroll
    for (int p = 0; p < 4; ++p) {
        int sid = p * 256 + tid;
        int r = sid >> 4, s = sid & 15;
        uint4 v = *reinterpret_cast<const uint4*>(Wt + (size_t)r * 128 + s * 8);
        *reinterpret_cast<uint4*>(&Ws[r * 128 + ((s ^ (r & 7)) * 8)]) = v;
    }
    __syncthreads();

    const int lane = tid & 63;
    const int wv   = tid >> 6;
    const int mrow = wv * 16 + (lane & 15);
    const int kg   = lane >> 4;

    half8 a[4];
#pragma unroll
    for (int kk = 0; kk < 4; ++kk)
        a[kk] = *reinterpret_cast<const half8*>(&As[mrow * 128 + (((kk * 4 + kg) ^ (mrow & 7)) * 8)]);

#pragma unroll
    for (int ct = 0; ct < 4; ++ct) {
        const int ncol = ct * 16 + (lane & 15);
        f32x4 acc = {0.f, 0.f, 0.f, 0.f};
#pragma unroll
        for (int kk = 0; kk < 4; ++kk) {
            half8 b = *reinterpret_cast<const half8*>(&Ws[ncol * 128 + (((kk * 4 + kg) ^ (ncol & 7)) * 8)]);
            acc = __builtin_amdgcn_mfma_f32_16x16x32_f16(a[kk], b, acc, 0, 0, 0);
        }
        const int grow = row0 + wv * 16 + kg * 4;
#pragma unroll
        for (int j = 0; j < 4; ++j)
            if (grow + j < nrows)
                C[(size_t)(grow + j) * 64 + ncol] = (_Float16)acc[j];
    }
}

// ================= gather-side GCN aggregation (fp16 tables) =================
__global__ __launch_bounds__(256) void k_agg1(const int* __restrict__ rp,
                                              const int* __restrict__ csrc,
                                              const float* __restrict__ dis,
                                              const __half* __restrict__ h1,
                                              const float* __restrict__ b,
                                              __half* __restrict__ out, int n) {
    const int lane = threadIdx.x & 63;
    const int node = blockIdx.x * 4 + (threadIdx.x >> 6);
    if (node >= n) return;
    const int start = rp[node], end = rp[node + 1];
    float ax = 0.f, ay = 0.f;
    int j = start;
    for (; j + 3 < end; j += 4) {
        int s0 = csrc[j], s1 = csrc[j + 1], s2 = csrc[j + 2], s3 = csrc[j + 3];
        float w0 = dis[s0], w1 = dis[s1], w2 = dis[s2], w3 = dis[s3];
        float2 f0 = __half22float2(*reinterpret_cast<const __half2*>(h1 + (size_t)s0 * 128 + lane * 2));
        float2 f1 = __half22float2(*reinterpret_cast<const __half2*>(h1 + (size_t)s1 * 128 + lane * 2));
        float2 f2 = __half22float2(*reinterpret_cast<const __half2*>(h1 + (size_t)s2 * 128 + lane * 2));
        float2 f3 = __half22float2(*reinterpret_cast<const __half2*>(h1 + (size_t)s3 * 128 + lane * 2));
        ax += w0 * f0.x + w1 * f1.x + w2 * f2.x + w3 * f3.x;
        ay += w0 * f0.y + w1 * f1.y + w2 * f2.y + w3 * f3.y;
    }
    for (; j < end; ++j) {
        int s0 = csrc[j];
        float w0 = dis[s0];
        float2 f0 = __half22float2(*reinterpret_cast<const __half2*>(h1 + (size_t)s0 * 128 + lane * 2));
        ax += w0 * f0.x;
        ay += w0 * f0.y;
    }
    const float dd = dis[node];
    const float di = 1.0f / (float)(end - start + 1);
    float2 hv = __half22float2(*reinterpret_cast<const __half2*>(h1 + (size_t)node * 128 + lane * 2));
    float2 bv = *reinterpret_cast<const float2*>(b + lane * 2);
    float ox = fmaxf(dd * ax + hv.x * di + bv.x, 0.f);
    float oy = fmaxf(dd * ay + hv.y * di + bv.y, 0.f);
    *reinterpret_cast<__half2*>(out + (size_t)node * 128 + lane * 2) = __floats2half2_rn(ox, oy);
}

__global__ __launch_bounds__(256) void k_agg2(const int* __restrict__ rp,
                                              const int* __restrict__ csrc,
                                              const float* __restrict__ dis,
                                              const __half* __restrict__ h2,
                                              const float* __restrict__ b,
                                              const __half* __restrict__ zmlp,
                                              float* __restrict__ out, int n) {
    const int lane = threadIdx.x & 63;
    const int node = blockIdx.x * 4 + (threadIdx.x >> 6);
    if (node >= n) return;
    const int start = rp[node], end = rp[node + 1];
    float acc = 0.f;
    int j = start;
    for (; j + 3 < end; j += 4) {
        int s0 = csrc[j], s1 = csrc[j + 1], s2 = csrc[j + 2], s3 = csrc[j + 3];
        acc += dis[s0] * __half2float(h2[(size_t)s0 * 64 + lane])
             + dis[s1] * __half2float(h2[(size_t)s1 * 64 + lane])
             + dis[s2] * __half2float(h2[(size_t)s2 * 64 + lane])
             + dis[s3] * __half2float(h2[(size_t)s3 * 64 + lane]);
    }
    for (; j < end; ++j) {
        int s0 = csrc[j];
        acc += dis[s0] * __half2float(h2[(size_t)s0 * 64 + lane]);
    }
    const float dd = dis[node];
    const float di = 1.0f / (float)(end - start + 1);
    float hv = __half2float(h2[(size_t)node * 64 + lane]);
    float zg = dd * acc + hv * di + b[lane];
    out[(size_t)node * 64 + lane] = 0.5f * (zg + __half2float(zmlp[(size_t)node * 64 + lane]));
}

extern "C" void kernel_launch(void* const* d_in, const int* in_sizes, int n_in,
                              void* d_out, int out_size, void* d_ws, size_t ws_size,
                              hipStream_t stream) {
    const float* x      = (const float*)d_in[0];
    const int* edge_idx = (const int*)d_in[1];
    const float* gnn_W1 = (const float*)d_in[2];
    const float* gnn_b1 = (const float*)d_in[3];
    const float* gnn_W2 = (const float*)d_in[4];
    const float* gnn_b2 = (const float*)d_in[5];
    const float* mlp_W1 = (const float*)d_in[6];
    const float* mlp_b1 = (const float*)d_in[7];
    const float* mlp_W2 = (const float*)d_in[8];
    const float* mlp_b2 = (const float*)d_in[9];
    float* out = (float*)d_out;

    const int N = in_sizes[0] / IN_F;
    const int E = in_sizes[1] / 2;
    const int* src = edge_idx;
    const int* dst = edge_idx + E;

    const int nb1 = (N + 255) / 256;          // scan blocks over N
    const int NB  = (N + 2047) >> 11;          // coarse buckets (<= 64 for N <= 131072)

    // ---- workspace layout ----
    char* wp = (char*)d_ws;
    int* row_ptr   = (int*)wp;            wp += ((size_t)N + 4) * sizeof(int);
    int* cursor    = (int*)wp;            wp += (size_t)N * sizeof(int);
    int* csr_src   = (int*)wp;            wp += (size_t)E * sizeof(int);
    int* blockSums = (int*)wp;            wp += 1024 * sizeof(int);
    int* bbase     = (int*)wp;            wp += 68 * sizeof(int);
    int* bcursor   = (int*)wp;            wp += 64 * sizeof(int);
    int* bcount    = (int*)wp;            wp += 64 * sizeof(int);
    int* hist      = (int*)wp;            wp += (size_t)N * sizeof(int);   // adjacent to bcount for one memset
    unsigned* recs = (unsigned*)wp;       wp += (size_t)E * sizeof(unsigned);
    float* dis     = (float*)wp;          wp += (size_t)N * sizeof(float);
    _Float16* tg1  = (_Float16*)wp;       wp += 16384 * sizeof(_Float16);
    _Float16* tm1  = (_Float16*)wp;       wp += 16384 * sizeof(_Float16);
    _Float16* tm2  = (_Float16*)wp;       wp += 8192 * sizeof(_Float16);
    _Float16* tg2  = (_Float16*)wp;       wp += 8192 * sizeof(_Float16);
    _Float16* h1   = (_Float16*)wp;       wp += (size_t)N * 128 * sizeof(_Float16);
    _Float16* hmid = (_Float16*)wp;       wp += (size_t)N * 128 * sizeof(_Float16);
    _Float16* h2   = (_Float16*)wp;       wp += (size_t)N * 64 * sizeof(_Float16);
    _Float16* zmlp = (_Float16*)wp;       wp += (size_t)N * 64 * sizeof(_Float16);

    // ---- weight prep ----
    k_prep_w<<<192, 256, 0, stream>>>(gnn_W1, mlp_W1, mlp_W2, gnn_W2, tg1, tm1, tm2, tg2);

    // ---- bucketed CSR build ----
    hipMemsetAsync(bcount, 0, (64 + (size_t)N) * sizeof(int), stream);  // bcount + hist
    const int mvblocks = (E + 4095) / 4096;
    kb_count<<<mvblocks, 1024, 0, stream>>>(dst, bcount, E);
    k_scanb<<<1, 64, 0, stream>>>(bcount, bbase, bcursor, NB);
    kb_move<<<mvblocks, 1024, 0, stream>>>(src, dst, bcursor, recs, E);
    k_histb<<<NB * CPB, 256, 0, stream>>>(recs, bbase, hist);
    k_scan1<<<nb1, 256, 0, stream>>>(hist, row_ptr, blockSums, N);
    k_scan2<<<1, 1024, 0, stream>>>(blockSums, nb1);
    k_scan3<<<nb1, 256, 0, stream>>>(row_ptr, blockSums, hist, cursor, dis, N, E);
    kb_fill<<<NB * CPB, 256, 0, stream>>>(recs, bbase, cursor, csr_src);

    const int gblocks = (N + 63) / 64;

    // ---- fused: h1 = x@gW1, zmlp = MLP(x) (one x pass) ----
    k_dual_mfma<<<gblocks, 256, 0, stream>>>(x, tg1, tm1, tm2, mlp_b1, mlp_b2, h1, zmlp, N);

    // ---- GNN layer 1 aggregation ----
    k_agg1<<<(N + 3) / 4, 256, 0, stream>>>(row_ptr, csr_src, dis, (const __half*)h1, gnn_b1,
                                            (__half*)hmid, N);

    // ---- h2 = hmid @ gW2 (MFMA) ----
    k_mm64<<<gblocks, 256, 0, stream>>>(hmid, tg2, h2, N);

    // ---- layer-2 aggregation fused with final mix ----
    k_agg2<<<(N + 3) / 4, 256, 0, stream>>>(row_ptr, csr_src, dis, (const __half*)h2, gnn_b2,
                                            (const __half*)zmlp, out, N);
}

// Round 7
// 362.136 us; speedup vs baseline: 19.1352x; 1.0647x over previous
//
#include <hip/hip_runtime.h>
#include <hip/hip_fp16.h>

static constexpr int IN_F = 128;
static constexpr int CPB  = 128;   // chunks (blocks) per bucket for histb/fill

typedef _Float16 half8 __attribute__((ext_vector_type(8)));
typedef _Float16 half4 __attribute__((ext_vector_type(4)));
typedef float f32x4 __attribute__((ext_vector_type(4)));

// ================= bucketed CSR build =================
// bucket b = dst >> 11  (2048 nodes/bucket, NB <= 64 for N <= 131072)
// record  = (dstLow:11 << 17) | src:17   (src < 2^17)

__global__ __launch_bounds__(1024) void kb_count(const int* __restrict__ dst,
                                                 int* __restrict__ bcount, int E) {
    __shared__ int cnt[64];
    const int tid = threadIdx.x;
    if (tid < 64) cnt[tid] = 0;
    __syncthreads();
#pragma unroll
    for (int q = 0; q < 4; ++q) {
        int i = blockIdx.x * 4096 + q * 1024 + tid;
        if (i < E) atomicAdd(&cnt[dst[i] >> 11], 1);
    }
    __syncthreads();
    if (tid < 64 && cnt[tid] > 0) atomicAdd(&bcount[tid], cnt[tid]);
}

__global__ __launch_bounds__(64) void k_scanb(const int* __restrict__ bcount,
                                              int* __restrict__ bbase,
                                              int* __restrict__ bcursor, int NB) {
    __shared__ int s[64];
    const int tid = threadIdx.x;
    int v = (tid < NB) ? bcount[tid] : 0;
    s[tid] = v;
    __syncthreads();
    int inc = v;
#pragma unroll
    for (int off = 1; off < 64; off <<= 1) {
        int add = (tid >= off) ? s[tid - off] : 0;
        __syncthreads();
        s[tid] = inc = inc + add;
        __syncthreads();
    }
    if (tid < NB) { bbase[tid] = inc - v; bcursor[tid] = inc - v; }
    if (tid == NB - 1) bbase[NB] = inc;   // total = E
}

__global__ __launch_bounds__(1024) void kb_move(const int* __restrict__ src,
                                                const int* __restrict__ dst,
                                                int* __restrict__ bcursor,
                                                unsigned* __restrict__ recs, int E) {
    __shared__ int cnt[64];
    __shared__ int off[64];
    const int tid = threadIdx.x;
    if (tid < 64) cnt[tid] = 0;
    __syncthreads();

    int bq[4];
    unsigned rq[4];
#pragma unroll
    for (int q = 0; q < 4; ++q) {
        int i = blockIdx.x * 4096 + q * 1024 + tid;
        if (i < E) {
            int d = dst[i];
            int s = src[i];
            bq[q] = d >> 11;
            rq[q] = (unsigned)(((d & 2047) << 17) | s);
            atomicAdd(&cnt[bq[q]], 1);
        } else {
            bq[q] = -1;
            rq[q] = 0u;
        }
    }
    __syncthreads();
    if (tid < 64 && cnt[tid] > 0) off[tid] = atomicAdd(&bcursor[tid], cnt[tid]);
    __syncthreads();
#pragma unroll
    for (int q = 0; q < 4; ++q) {
        if (bq[q] >= 0) {
            int p = atomicAdd(&off[bq[q]], 1);
            recs[p] = rq[q];
        }
    }
}

__global__ __launch_bounds__(256) void k_histb(const unsigned* __restrict__ recs,
                                               const int* __restrict__ bbase,
                                               int* __restrict__ hist) {
    const int b = blockIdx.x / CPB;
    const int c = blockIdx.x % CPB;
    const int s = bbase[b], e = bbase[b + 1];
    const int nbase = b << 11;
    for (int i = s + c * 256 + threadIdx.x; i < e; i += CPB * 256)
        atomicAdd(&hist[nbase + (int)(recs[i] >> 17)], 1);
}

// fill CSR records {src, f32bits(dis[src])}
__global__ __launch_bounds__(256) void kb_fill(const unsigned* __restrict__ recs,
                                               const int* __restrict__ bbase,
                                               int* __restrict__ cursor,
                                               int2* __restrict__ csr,
                                               const float* __restrict__ dis) {
    const int b = blockIdx.x / CPB;
    const int c = blockIdx.x % CPB;
    const int s = bbase[b], e = bbase[b + 1];
    const int nbase = b << 11;
    for (int i = s + c * 256 + threadIdx.x; i < e; i += CPB * 256) {
        unsigned r = recs[i];
        int d  = nbase + (int)(r >> 17);
        int sr = (int)(r & 0x1FFFFu);
        int slot = atomicAdd(&cursor[d], 1);
        csr[slot] = make_int2(sr, __float_as_int(dis[sr]));
    }
}

// ================= scans over N =================
__global__ __launch_bounds__(256) void k_scan1(const int* __restrict__ hist,
                                               int* __restrict__ row_ptr,
                                               int* __restrict__ blockSums, int n) {
    __shared__ int s[256];
    int tid = threadIdx.x;
    int i   = blockIdx.x * 256 + tid;
    int v   = (i < n) ? hist[i] : 0;
    s[tid] = v;
    __syncthreads();
    int inc = v;
#pragma unroll
    for (int off = 1; off < 256; off <<= 1) {
        int add = (tid >= off) ? s[tid - off] : 0;
        __syncthreads();
        s[tid] = inc = inc + add;
        __syncthreads();
    }
    if (i < n) row_ptr[i] = inc - v;
    if (tid == 255) blockSums[blockIdx.x] = inc;
}

__global__ __launch_bounds__(1024) void k_scan2(int* __restrict__ blockSums, int nb) {
    __shared__ int s[1024];
    int tid = threadIdx.x;
    int v = (tid < nb) ? blockSums[tid] : 0;
    s[tid] = v;
    __syncthreads();
    int inc = v;
#pragma unroll
    for (int off = 1; off < 1024; off <<= 1) {
        int add = (tid >= off) ? s[tid - off] : 0;
        __syncthreads();
        s[tid] = inc = inc + add;
        __syncthreads();
    }
    if (tid < nb) blockSums[tid] = inc - v;
}

__global__ __launch_bounds__(256) void k_scan3(int* __restrict__ row_ptr,
                                               const int* __restrict__ blockSums,
                                               const int* __restrict__ hist,
                                               int* __restrict__ cursor,
                                               float* __restrict__ dis, int n, int E) {
    int i = blockIdx.x * 256 + threadIdx.x;
    if (i < n) {
        int rp = row_ptr[i] + blockSums[i >> 8];
        row_ptr[i] = rp;
        cursor[i]  = rp;
        dis[i] = rsqrtf(1.0f + (float)hist[i]);
    }
    if (i == 0) row_ptr[n] = E;
}

// ================= weight prep: f32 [K][F] -> fp16 [F][K] =================
__global__ __launch_bounds__(256) void k_prep_w(const float* __restrict__ gW1,
                                                const float* __restrict__ mW1,
                                                const float* __restrict__ mW2,
                                                const float* __restrict__ gW2,
                                                _Float16* __restrict__ tg1,
                                                _Float16* __restrict__ tm1,
                                                _Float16* __restrict__ tm2,
                                                _Float16* __restrict__ tg2) {
    int i = blockIdx.x * 256 + threadIdx.x;
    if (i < 16384)      { int j = i;         int f = j >> 7, k = j & 127; tg1[j] = (_Float16)gW1[k * 128 + f]; }
    else if (i < 32768) { int j = i - 16384; int f = j >> 7, k = j & 127; tm1[j] = (_Float16)mW1[k * 128 + f]; }
    else if (i < 40960) { int j = i - 32768; int f = j >> 7, k = j & 127; tm2[j] = (_Float16)mW2[k * 64 + f]; }
    else if (i < 49152) { int j = i - 40960; int f = j >> 7, k = j & 127; tg2[j] = (_Float16)gW2[k * 64 + f]; }
}

// ============ fused MFMA: h1 = x@gW1, z = relu(x@mW1+b1)@mW2+b2 ============
__global__ __launch_bounds__(256) void k_dual_mfma(const float* __restrict__ x,
                                                   const _Float16* __restrict__ tg1,
                                                   const _Float16* __restrict__ tm1,
                                                   const _Float16* __restrict__ tm2,
                                                   const float* __restrict__ b1,
                                                   const float* __restrict__ b2,
                                                   _Float16* __restrict__ h1,
                                                   _Float16* __restrict__ z, int nrows) {
    __shared__ _Float16 As[64 * 128];    // 16 KB
    __shared__ _Float16 Ws[128 * 128];   // 32 KB
    __shared__ _Float16 Ms[64 * 128];    // 16 KB
    const int tid  = threadIdx.x;
    const int row0 = blockIdx.x * 64;

#pragma unroll
    for (int p = 0; p < 4; ++p) {
        int sid = p * 256 + tid;
        int r = sid >> 4, s = sid & 15;
        int gr = row0 + r;
        uint4 v = make_uint4(0, 0, 0, 0);
        if (gr < nrows) {
            const float4 f0 = *reinterpret_cast<const float4*>(x + (size_t)gr * 128 + s * 8);
            const float4 f1 = *reinterpret_cast<const float4*>(x + (size_t)gr * 128 + s * 8 + 4);
            _Float16 t[8] = {(_Float16)f0.x, (_Float16)f0.y, (_Float16)f0.z, (_Float16)f0.w,
                             (_Float16)f1.x, (_Float16)f1.y, (_Float16)f1.z, (_Float16)f1.w};
            v = *reinterpret_cast<uint4*>(t);
        }
        *reinterpret_cast<uint4*>(&As[r * 128 + ((s ^ (r & 7)) * 8)]) = v;
    }
#pragma unroll
    for (int p = 0; p < 8; ++p) {
        int sid = p * 256 + tid;
        int r = sid >> 4, s = sid & 15;
        uint4 v = *reinterpret_cast<const uint4*>(tg1 + (size_t)r * 128 + s * 8);
        *reinterpret_cast<uint4*>(&Ws[r * 128 + ((s ^ (r & 7)) * 8)]) = v;
    }
    __syncthreads();

    const int lane = tid & 63;
    const int wv   = tid >> 6;
    const int mrow = wv * 16 + (lane & 15);
    const int kg   = lane >> 4;

    half8 a[4];
#pragma unroll
    for (int kk = 0; kk < 4; ++kk)
        a[kk] = *reinterpret_cast<const half8*>(&As[mrow * 128 + (((kk * 4 + kg) ^ (mrow & 7)) * 8)]);

    // phase 1: h1 = x @ gW1
#pragma unroll
    for (int ct = 0; ct < 8; ++ct) {
        const int ncol = ct * 16 + (lane & 15);
        f32x4 acc = {0.f, 0.f, 0.f, 0.f};
#pragma unroll
        for (int kk = 0; kk < 4; ++kk) {
            half8 b = *reinterpret_cast<const half8*>(&Ws[ncol * 128 + (((kk * 4 + kg) ^ (ncol & 7)) * 8)]);
            acc = __builtin_amdgcn_mfma_f32_16x16x32_f16(a[kk], b, acc, 0, 0, 0);
        }
        const int grow = row0 + wv * 16 + kg * 4;
#pragma unroll
        for (int j = 0; j < 4; ++j)
            if (grow + j < nrows)
                h1[(size_t)(grow + j) * 128 + ncol] = (_Float16)acc[j];
    }
    __syncthreads();

#pragma unroll
    for (int p = 0; p < 8; ++p) {
        int sid = p * 256 + tid;
        int r = sid >> 4, s = sid & 15;
        uint4 v = *reinterpret_cast<const uint4*>(tm1 + (size_t)r * 128 + s * 8);
        *reinterpret_cast<uint4*>(&Ws[r * 128 + ((s ^ (r & 7)) * 8)]) = v;
    }
    __syncthreads();

    // phase 2: M = relu(x@mW1 + b1) -> Ms (swizzled fp16)
#pragma unroll
    for (int ct = 0; ct < 8; ++ct) {
        const int ncol = ct * 16 + (lane & 15);
        f32x4 acc = {0.f, 0.f, 0.f, 0.f};
#pragma unroll
        for (int kk = 0; kk < 4; ++kk) {
            half8 b = *reinterpret_cast<const half8*>(&Ws[ncol * 128 + (((kk * 4 + kg) ^ (ncol & 7)) * 8)]);
            acc = __builtin_amdgcn_mfma_f32_16x16x32_f16(a[kk], b, acc, 0, 0, 0);
        }
        const float bias = b1[ncol];
#pragma unroll
        for (int j = 0; j < 4; ++j) {
            int r = wv * 16 + kg * 4 + j;
            float v = fmaxf((float)acc[j] + bias, 0.f);
            Ms[r * 128 + (((ncol >> 3) ^ (r & 7)) * 8) + (ncol & 7)] = (_Float16)v;
        }
    }
    __syncthreads();

#pragma unroll
    for (int p = 0; p < 4; ++p) {
        int sid = p * 256 + tid;
        int r = sid >> 4, s = sid & 15;
        uint4 v = *reinterpret_cast<const uint4*>(tm2 + (size_t)r * 128 + s * 8);
        *reinterpret_cast<uint4*>(&Ws[r * 128 + ((s ^ (r & 7)) * 8)]) = v;
    }
    __syncthreads();

    // phase 3: z = M @ mW2 + b2 (F=64)
    half8 am[4];
#pragma unroll
    for (int kk = 0; kk < 4; ++kk)
        am[kk] = *reinterpret_cast<const half8*>(&Ms[mrow * 128 + (((kk * 4 + kg) ^ (mrow & 7)) * 8)]);

#pragma unroll
    for (int ct = 0; ct < 4; ++ct) {
        const int ncol = ct * 16 + (lane & 15);
        f32x4 acc = {0.f, 0.f, 0.f, 0.f};
#pragma unroll
        for (int kk = 0; kk < 4; ++kk) {
            half8 b = *reinterpret_cast<const half8*>(&Ws[ncol * 128 + (((kk * 4 + kg) ^ (ncol & 7)) * 8)]);
            acc = __builtin_amdgcn_mfma_f32_16x16x32_f16(am[kk], b, acc, 0, 0, 0);
        }
        const float bias = b2[ncol];
        const int grow = row0 + wv * 16 + kg * 4;
#pragma unroll
        for (int j = 0; j < 4; ++j)
            if (grow + j < nrows)
                z[(size_t)(grow + j) * 64 + ncol] = (_Float16)((float)acc[j] + bias);
    }
}

// ============ MFMA GEMM: h2 = hmid @ gW2 (fp16 in/out), F=64 ============
__global__ __launch_bounds__(256) void k_mm64(const _Float16* __restrict__ A,
                                              const _Float16* __restrict__ Wt,
                                              _Float16* __restrict__ C, int nrows) {
    __shared__ _Float16 As[64 * 128];
    __shared__ _Float16 Ws[64 * 128];
    const int tid  = threadIdx.x;
    const int row0 = blockIdx.x * 64;

#pragma unroll
    for (int p = 0; p < 4; ++p) {
        int sid = p * 256 + tid;
        int r = sid >> 4, s = sid & 15;
        int gr = row0 + r;
        uint4 v = make_uint4(0, 0, 0, 0);
        if (gr < nrows) v = *reinterpret_cast<const uint4*>(A + (size_t)gr * 128 + s * 8);
        *reinterpret_cast<uint4*>(&As[r * 128 + ((s ^ (r & 7)) * 8)]) = v;
    }
#pragma unroll
    for (int p = 0; p < 4; ++p) {
        int sid = p * 256 + tid;
        int r = sid >> 4, s = sid & 15;
        uint4 v = *reinterpret_cast<const uint4*>(Wt + (size_t)r * 128 + s * 8);
        *reinterpret_cast<uint4*>(&Ws[r * 128 + ((s ^ (r & 7)) * 8)]) = v;
    }
    __syncthreads();

    const int lane = tid & 63;
    const int wv   = tid >> 6;
    const int mrow = wv * 16 + (lane & 15);
    const int kg   = lane >> 4;

    half8 a[4];
#pragma unroll
    for (int kk = 0; kk < 4; ++kk)
        a[kk] = *reinterpret_cast<const half8*>(&As[mrow * 128 + (((kk * 4 + kg) ^ (mrow & 7)) * 8)]);

#pragma unroll
    for (int ct = 0; ct < 4; ++ct) {
        const int ncol = ct * 16 + (lane & 15);
        f32x4 acc = {0.f, 0.f, 0.f, 0.f};
#pragma unroll
        for (int kk = 0; kk < 4; ++kk) {
            half8 b = *reinterpret_cast<const half8*>(&Ws[ncol * 128 + (((kk * 4 + kg) ^ (ncol & 7)) * 8)]);
            acc = __builtin_amdgcn_mfma_f32_16x16x32_f16(a[kk], b, acc, 0, 0, 0);
        }
        const int grow = row0 + wv * 16 + kg * 4;
#pragma unroll
        for (int j = 0; j < 4; ++j)
            if (grow + j < nrows)
                C[(size_t)(grow + j) * 64 + ncol] = (_Float16)acc[j];
    }
}

// ================= gather aggregation: 4 edges in flight per wave =================
// layer 1: F=128. 16-lane groups, half8 (16B) per lane per edge row.
__global__ __launch_bounds__(256) void k_agg1(const int* __restrict__ rp,
                                              const int2* __restrict__ csr,
                                              const float* __restrict__ dis,
                                              const _Float16* __restrict__ h1,
                                              const float* __restrict__ b,
                                              _Float16* __restrict__ out, int n) {
    const int tid  = threadIdx.x;
    const int node = blockIdx.x * 4 + (tid >> 6);
    if (node >= n) return;
    const int lane = tid & 63;
    const int g    = lane >> 4;          // edge group 0..3
    const int c0   = (lane & 15) * 8;    // 8 feature cols per lane
    const int start = rp[node], end = rp[node + 1];

    float acc[8];
#pragma unroll
    for (int k = 0; k < 8; ++k) acc[k] = 0.f;

    int j = start + g;
    for (; j + 4 < end; j += 8) {
        int2 e0 = csr[j];
        int2 e1 = csr[j + 4];
        float w0 = __int_as_float(e0.y);
        float w1 = __int_as_float(e1.y);
        half8 v0 = *reinterpret_cast<const half8*>(h1 + (size_t)e0.x * 128 + c0);
        half8 v1 = *reinterpret_cast<const half8*>(h1 + (size_t)e1.x * 128 + c0);
#pragma unroll
        for (int k = 0; k < 8; ++k)
            acc[k] += w0 * (float)v0[k] + w1 * (float)v1[k];
    }
    if (j < end) {
        int2 e0 = csr[j];
        float w0 = __int_as_float(e0.y);
        half8 v0 = *reinterpret_cast<const half8*>(h1 + (size_t)e0.x * 128 + c0);
#pragma unroll
        for (int k = 0; k < 8; ++k) acc[k] += w0 * (float)v0[k];
    }

#pragma unroll
    for (int k = 0; k < 8; ++k) {
        acc[k] += __shfl_xor(acc[k], 16);
        acc[k] += __shfl_xor(acc[k], 32);
    }

    if (g == 0) {
        const float dd = dis[node];
        const float di = 1.0f / (float)(end - start + 1);
        half8 hv = *reinterpret_cast<const half8*>(h1 + (size_t)node * 128 + c0);
        const float4 bv0 = *reinterpret_cast<const float4*>(b + c0);
        const float4 bv1 = *reinterpret_cast<const float4*>(b + c0 + 4);
        const float bb[8] = {bv0.x, bv0.y, bv0.z, bv0.w, bv1.x, bv1.y, bv1.z, bv1.w};
        half8 o;
#pragma unroll
        for (int k = 0; k < 8; ++k)
            o[k] = (_Float16)fmaxf(dd * acc[k] + (float)hv[k] * di + bb[k], 0.f);
        *reinterpret_cast<half8*>(out + (size_t)node * 128 + c0) = o;
    }
}

// layer 2 + final fuse: F=64. 16-lane groups, half4 (8B) per lane per edge row.
__global__ __launch_bounds__(256) void k_agg2(const int* __restrict__ rp,
                                              const int2* __restrict__ csr,
                                              const float* __restrict__ dis,
                                              const _Float16* __restrict__ h2,
                                              const float* __restrict__ b,
                                              const _Float16* __restrict__ zmlp,
                                              float* __restrict__ out, int n) {
    const int tid  = threadIdx.x;
    const int node = blockIdx.x * 4 + (tid >> 6);
    if (node >= n) return;
    const int lane = tid & 63;
    const int g    = lane >> 4;
    const int c0   = (lane & 15) * 4;
    const int start = rp[node], end = rp[node + 1];

    float acc[4];
#pragma unroll
    for (int k = 0; k < 4; ++k) acc[k] = 0.f;

    int j = start + g;
    for (; j + 4 < end; j += 8) {
        int2 e0 = csr[j];
        int2 e1 = csr[j + 4];
        float w0 = __int_as_float(e0.y);
        float w1 = __int_as_float(e1.y);
        half4 v0 = *reinterpret_cast<const half4*>(h2 + (size_t)e0.x * 64 + c0);
        half4 v1 = *reinterpret_cast<const half4*>(h2 + (size_t)e1.x * 64 + c0);
#pragma unroll
        for (int k = 0; k < 4; ++k)
            acc[k] += w0 * (float)v0[k] + w1 * (float)v1[k];
    }
    if (j < end) {
        int2 e0 = csr[j];
        float w0 = __int_as_float(e0.y);
        half4 v0 = *reinterpret_cast<const half4*>(h2 + (size_t)e0.x * 64 + c0);
#pragma unroll
        for (int k = 0; k < 4; ++k) acc[k] += w0 * (float)v0[k];
    }

#pragma unroll
    for (int k = 0; k < 4; ++k) {
        acc[k] += __shfl_xor(acc[k], 16);
        acc[k] += __shfl_xor(acc[k], 32);
    }

    if (g == 0) {
        const float dd = dis[node];
        const float di = 1.0f / (float)(end - start + 1);
        half4 hv = *reinterpret_cast<const half4*>(h2 + (size_t)node * 64 + c0);
        half4 zm = *reinterpret_cast<const half4*>(zmlp + (size_t)node * 64 + c0);
        const float4 bv = *reinterpret_cast<const float4*>(b + c0);
        const float bb[4] = {bv.x, bv.y, bv.z, bv.w};
        float4 o;
        float* op = &o.x;
#pragma unroll
        for (int k = 0; k < 4; ++k)
            op[k] = 0.5f * ((dd * acc[k] + (float)hv[k] * di + bb[k]) + (float)zm[k]);
        *reinterpret_cast<float4*>(out + (size_t)node * 64 + c0) = o;
    }
}

extern "C" void kernel_launch(void* const* d_in, const int* in_sizes, int n_in,
                              void* d_out, int out_size, void* d_ws, size_t ws_size,
                              hipStream_t stream) {
    const float* x      = (const float*)d_in[0];
    const int* edge_idx = (const int*)d_in[1];
    const float* gnn_W1 = (const float*)d_in[2];
    const float* gnn_b1 = (const float*)d_in[3];
    const float* gnn_W2 = (const float*)d_in[4];
    const float* gnn_b2 = (const float*)d_in[5];
    const float* mlp_W1 = (const float*)d_in[6];
    const float* mlp_b1 = (const float*)d_in[7];
    const float* mlp_W2 = (const float*)d_in[8];
    const float* mlp_b2 = (const float*)d_in[9];
    float* out = (float*)d_out;

    const int N = in_sizes[0] / IN_F;
    const int E = in_sizes[1] / 2;
    const int* src = edge_idx;
    const int* dst = edge_idx + E;

    const int nb1 = (N + 255) / 256;
    const int NB  = (N + 2047) >> 11;

    // ---- workspace layout ----
    char* wp = (char*)d_ws;
    int* row_ptr   = (int*)wp;            wp += ((size_t)N + 4) * sizeof(int);
    int* cursor    = (int*)wp;            wp += (size_t)N * sizeof(int);
    int* blockSums = (int*)wp;            wp += 1024 * sizeof(int);
    int* bbase     = (int*)wp;            wp += 68 * sizeof(int);
    int* bcursor   = (int*)wp;            wp += 64 * sizeof(int);
    int* bcount    = (int*)wp;            wp += 64 * sizeof(int);
    int* hist      = (int*)wp;            wp += (size_t)N * sizeof(int);   // adjacent to bcount for one memset
    unsigned* recs = (unsigned*)wp;       wp += (size_t)E * sizeof(unsigned);
    float* dis     = (float*)wp;          wp += (size_t)N * sizeof(float);
    wp = (char*)(((uintptr_t)wp + 15) & ~(uintptr_t)15);
    int2* csr      = (int2*)wp;           wp += (size_t)E * sizeof(int2);
    _Float16* tg1  = (_Float16*)wp;       wp += 16384 * sizeof(_Float16);
    _Float16* tm1  = (_Float16*)wp;       wp += 16384 * sizeof(_Float16);
    _Float16* tm2  = (_Float16*)wp;       wp += 8192 * sizeof(_Float16);
    _Float16* tg2  = (_Float16*)wp;       wp += 8192 * sizeof(_Float16);
    _Float16* h1   = (_Float16*)wp;       wp += (size_t)N * 128 * sizeof(_Float16);
    _Float16* hmid = (_Float16*)wp;       wp += (size_t)N * 128 * sizeof(_Float16);
    _Float16* h2   = (_Float16*)wp;       wp += (size_t)N * 64 * sizeof(_Float16);
    _Float16* zmlp = (_Float16*)wp;       wp += (size_t)N * 64 * sizeof(_Float16);

    // ---- weight prep ----
    k_prep_w<<<192, 256, 0, stream>>>(gnn_W1, mlp_W1, mlp_W2, gnn_W2, tg1, tm1, tm2, tg2);

    // ---- bucketed CSR build ----
    hipMemsetAsync(bcount, 0, (64 + (size_t)N) * sizeof(int), stream);  // bcount + hist
    const int mvblocks = (E + 4095) / 4096;
    kb_count<<<mvblocks, 1024, 0, stream>>>(dst, bcount, E);
    k_scanb<<<1, 64, 0, stream>>>(bcount, bbase, bcursor, NB);
    kb_move<<<mvblocks, 1024, 0, stream>>>(src, dst, bcursor, recs, E);
    k_histb<<<NB * CPB, 256, 0, stream>>>(recs, bbase, hist);
    k_scan1<<<nb1, 256, 0, stream>>>(hist, row_ptr, blockSums, N);
    k_scan2<<<1, 1024, 0, stream>>>(blockSums, nb1);
    k_scan3<<<nb1, 256, 0, stream>>>(row_ptr, blockSums, hist, cursor, dis, N, E);
    kb_fill<<<NB * CPB, 256, 0, stream>>>(recs, bbase, cursor, csr, dis);

    const int gblocks = (N + 63) / 64;

    // ---- fused: h1 = x@gW1, zmlp = MLP(x) (one x pass) ----
    k_dual_mfma<<<gblocks, 256, 0, stream>>>(x, tg1, tm1, tm2, mlp_b1, mlp_b2, h1, zmlp, N);

    // ---- GNN layer 1 aggregation ----
    k_agg1<<<(N + 3) / 4, 256, 0, stream>>>(row_ptr, csr, dis, h1, gnn_b1, hmid, N);

    // ---- h2 = hmid @ gW2 (MFMA) ----
    k_mm64<<<gblocks, 256, 0, stream>>>(hmid, tg2, h2, N);

    // ---- layer-2 aggregation fused with final mix ----
    k_agg2<<<(N + 3) / 4, 256, 0, stream>>>(row_ptr, csr, dis, h2, gnn_b2, zmlp, out, N);
}

// Round 8
// 242.022 us; speedup vs baseline: 28.6318x; 1.4963x over previous
//
#include <hip/hip_runtime.h>
#include <hip/hip_fp16.h>

static constexpr int IN_F = 128;
static constexpr int FCAP = 6144;   // staged records per bucket (avg ~4090, +30σ headroom)

typedef _Float16 half8 __attribute__((ext_vector_type(8)));
typedef _Float16 half4 __attribute__((ext_vector_type(4)));
typedef float f32x4 __attribute__((ext_vector_type(4)));

// ================= bucketed CSR build =================
// bucket b = dst >> 8 (256 nodes/bucket, NB <= 512 for N <= 131072)
// record  = (dstLow:8 << 17) | src:17   (src < 2^17)

__global__ __launch_bounds__(1024) void kb_count(const int* __restrict__ dst,
                                                 int* __restrict__ bcount, int E) {
    __shared__ int cnt[512];
    const int tid = threadIdx.x;
    if (tid < 512) cnt[tid] = 0;
    __syncthreads();
#pragma unroll
    for (int q = 0; q < 8; ++q) {
        int i = blockIdx.x * 8192 + q * 1024 + tid;
        if (i < E) atomicAdd(&cnt[dst[i] >> 8], 1);
    }
    __syncthreads();
    if (tid < 512 && cnt[tid] > 0) atomicAdd(&bcount[tid], cnt[tid]);
}

__global__ __launch_bounds__(512) void k_scanb(const int* __restrict__ bcount,
                                               int* __restrict__ bbase,
                                               int* __restrict__ bcursor, int NB) {
    __shared__ int s[512];
    const int tid = threadIdx.x;
    int v = (tid < NB) ? bcount[tid] : 0;
    s[tid] = v;
    __syncthreads();
    int inc = v;
#pragma unroll
    for (int off = 1; off < 512; off <<= 1) {
        int add = (tid >= off) ? s[tid - off] : 0;
        __syncthreads();
        s[tid] = inc = inc + add;
        __syncthreads();
    }
    if (tid < NB) { bbase[tid] = inc - v; bcursor[tid] = inc - v; }
    if (tid == NB - 1) bbase[NB] = inc;   // total = E
}

__global__ __launch_bounds__(1024) void kb_move(const int* __restrict__ src,
                                                const int* __restrict__ dst,
                                                int* __restrict__ bcursor,
                                                unsigned* __restrict__ recs, int E) {
    __shared__ int cnt[512];
    __shared__ int off[512];
    const int tid = threadIdx.x;
    if (tid < 512) cnt[tid] = 0;
    __syncthreads();

    int bq[8];
    unsigned rq[8];
#pragma unroll
    for (int q = 0; q < 8; ++q) {
        int i = blockIdx.x * 8192 + q * 1024 + tid;
        if (i < E) {
            int d = dst[i];
            int s = src[i];
            bq[q] = d >> 8;
            rq[q] = (unsigned)(((d & 255) << 17) | s);
            atomicAdd(&cnt[bq[q]], 1);
        } else {
            bq[q] = -1;
            rq[q] = 0u;
        }
    }
    __syncthreads();
    if (tid < 512 && cnt[tid] > 0) off[tid] = atomicAdd(&bcursor[tid], cnt[tid]);
    __syncthreads();
#pragma unroll
    for (int q = 0; q < 8; ++q) {
        if (bq[q] >= 0) {
            int p = atomicAdd(&off[bq[q]], 1);
            recs[p] = rq[q];
        }
    }
}

// one block per bucket: hist -> scan -> row_ptr/dis -> LDS place -> coalesced stream
__global__ __launch_bounds__(256) void kb_fill_lds(const unsigned* __restrict__ recs,
                                                   const int* __restrict__ bbase,
                                                   int* __restrict__ row_ptr,
                                                   float* __restrict__ dis,
                                                   int* __restrict__ csr, int n) {
    __shared__ int hist[256];
    __shared__ int sc[256];
    __shared__ int base[257];
    __shared__ int cur[256];
    __shared__ int stage[FCAP];
    const int tid   = threadIdx.x;
    const int b     = blockIdx.x;
    const int s     = bbase[b], e = bbase[b + 1];
    const int nbase = b << 8;

    hist[tid] = 0;
    __syncthreads();
    for (int i = s + tid; i < e; i += 256)
        atomicAdd(&hist[recs[i] >> 17], 1);
    __syncthreads();

    // exclusive block scan of hist
    const int v = hist[tid];
    sc[tid] = v;
    __syncthreads();
    int inc = v;
#pragma unroll
    for (int off = 1; off < 256; off <<= 1) {
        int add = (tid >= off) ? sc[tid - off] : 0;
        __syncthreads();
        sc[tid] = inc = inc + add;
        __syncthreads();
    }
    const int excl = inc - v;
    base[tid] = excl;
    if (tid == 255) base[256] = inc;
    cur[tid] = 0;

    // row_ptr + dis for this bucket (replaces global hist/scan passes)
    const int idx = nbase + tid;
    if (idx < n) {
        row_ptr[idx] = s + excl;
        dis[idx] = rsqrtf(1.0f + (float)v);
    }
    if (idx == n) row_ptr[n] = s + excl;                        // N not multiple of 256
    if (tid == 255 && nbase + 256 == n) row_ptr[n] = s + inc;   // N multiple of 256
    __syncthreads();

    // place into LDS staging at sorted slot
    for (int i = s + tid; i < e; i += 256) {
        unsigned r = recs[i];
        int dl = (int)(r >> 17);
        int slot = base[dl] + atomicAdd(&cur[dl], 1);
        int sr = (int)(r & 0x1FFFFu);
        if (slot < FCAP) stage[slot] = sr;
        else csr[s + slot] = sr;    // overflow fallback (never hit for uniform graphs)
    }
    __syncthreads();

    // stream out coalesced
    const int total = e - s;
    const int lim = total < FCAP ? total : FCAP;
    for (int i = tid; i < lim; i += 256)
        csr[s + i] = stage[i];
}

// ================= weight prep: f32 [K][F] -> fp16 [F][K] =================
__global__ __launch_bounds__(256) void k_prep_w(const float* __restrict__ gW1,
                                                const float* __restrict__ mW1,
                                                const float* __restrict__ mW2,
                                                const float* __restrict__ gW2,
                                                _Float16* __restrict__ tg1,
                                                _Float16* __restrict__ tm1,
                                                _Float16* __restrict__ tm2,
                                                _Float16* __restrict__ tg2) {
    int i = blockIdx.x * 256 + threadIdx.x;
    if (i < 16384)      { int j = i;         int f = j >> 7, k = j & 127; tg1[j] = (_Float16)gW1[k * 128 + f]; }
    else if (i < 32768) { int j = i - 16384; int f = j >> 7, k = j & 127; tm1[j] = (_Float16)mW1[k * 128 + f]; }
    else if (i < 40960) { int j = i - 32768; int f = j >> 7, k = j & 127; tm2[j] = (_Float16)mW2[k * 64 + f]; }
    else if (i < 49152) { int j = i - 40960; int f = j >> 7, k = j & 127; tg2[j] = (_Float16)gW2[k * 64 + f]; }
}

// ============ fused MFMA: h1 = x@gW1, z = relu(x@mW1+b1)@mW2+b2 ============
__global__ __launch_bounds__(256) void k_dual_mfma(const float* __restrict__ x,
                                                   const _Float16* __restrict__ tg1,
                                                   const _Float16* __restrict__ tm1,
                                                   const _Float16* __restrict__ tm2,
                                                   const float* __restrict__ b1,
                                                   const float* __restrict__ b2,
                                                   _Float16* __restrict__ h1,
                                                   _Float16* __restrict__ z, int nrows) {
    __shared__ _Float16 As[64 * 128];    // 16 KB
    __shared__ _Float16 Ws[128 * 128];   // 32 KB
    __shared__ _Float16 Ms[64 * 128];    // 16 KB
    const int tid  = threadIdx.x;
    const int row0 = blockIdx.x * 64;

#pragma unroll
    for (int p = 0; p < 4; ++p) {
        int sid = p * 256 + tid;
        int r = sid >> 4, s = sid & 15;
        int gr = row0 + r;
        uint4 v = make_uint4(0, 0, 0, 0);
        if (gr < nrows) {
            const float4 f0 = *reinterpret_cast<const float4*>(x + (size_t)gr * 128 + s * 8);
            const float4 f1 = *reinterpret_cast<const float4*>(x + (size_t)gr * 128 + s * 8 + 4);
            _Float16 t[8] = {(_Float16)f0.x, (_Float16)f0.y, (_Float16)f0.z, (_Float16)f0.w,
                             (_Float16)f1.x, (_Float16)f1.y, (_Float16)f1.z, (_Float16)f1.w};
            v = *reinterpret_cast<uint4*>(t);
        }
        *reinterpret_cast<uint4*>(&As[r * 128 + ((s ^ (r & 7)) * 8)]) = v;
    }
#pragma unroll
    for (int p = 0; p < 8; ++p) {
        int sid = p * 256 + tid;
        int r = sid >> 4, s = sid & 15;
        uint4 v = *reinterpret_cast<const uint4*>(tg1 + (size_t)r * 128 + s * 8);
        *reinterpret_cast<uint4*>(&Ws[r * 128 + ((s ^ (r & 7)) * 8)]) = v;
    }
    __syncthreads();

    const int lane = tid & 63;
    const int wv   = tid >> 6;
    const int mrow = wv * 16 + (lane & 15);
    const int kg   = lane >> 4;

    half8 a[4];
#pragma unroll
    for (int kk = 0; kk < 4; ++kk)
        a[kk] = *reinterpret_cast<const half8*>(&As[mrow * 128 + (((kk * 4 + kg) ^ (mrow & 7)) * 8)]);

    // phase 1: h1 = x @ gW1
#pragma unroll
    for (int ct = 0; ct < 8; ++ct) {
        const int ncol = ct * 16 + (lane & 15);
        f32x4 acc = {0.f, 0.f, 0.f, 0.f};
#pragma unroll
        for (int kk = 0; kk < 4; ++kk) {
            half8 b = *reinterpret_cast<const half8*>(&Ws[ncol * 128 + (((kk * 4 + kg) ^ (ncol & 7)) * 8)]);
            acc = __builtin_amdgcn_mfma_f32_16x16x32_f16(a[kk], b, acc, 0, 0, 0);
        }
        const int grow = row0 + wv * 16 + kg * 4;
#pragma unroll
        for (int j = 0; j < 4; ++j)
            if (grow + j < nrows)
                h1[(size_t)(grow + j) * 128 + ncol] = (_Float16)acc[j];
    }
    __syncthreads();

#pragma unroll
    for (int p = 0; p < 8; ++p) {
        int sid = p * 256 + tid;
        int r = sid >> 4, s = sid & 15;
        uint4 v = *reinterpret_cast<const uint4*>(tm1 + (size_t)r * 128 + s * 8);
        *reinterpret_cast<uint4*>(&Ws[r * 128 + ((s ^ (r & 7)) * 8)]) = v;
    }
    __syncthreads();

    // phase 2: M = relu(x@mW1 + b1) -> Ms (swizzled fp16)
#pragma unroll
    for (int ct = 0; ct < 8; ++ct) {
        const int ncol = ct * 16 + (lane & 15);
        f32x4 acc = {0.f, 0.f, 0.f, 0.f};
#pragma unroll
        for (int kk = 0; kk < 4; ++kk) {
            half8 b = *reinterpret_cast<const half8*>(&Ws[ncol * 128 + (((kk * 4 + kg) ^ (ncol & 7)) * 8)]);
            acc = __builtin_amdgcn_mfma_f32_16x16x32_f16(a[kk], b, acc, 0, 0, 0);
        }
        const float bias = b1[ncol];
#pragma unroll
        for (int j = 0; j < 4; ++j) {
            int r = wv * 16 + kg * 4 + j;
            float v = fmaxf((float)acc[j] + bias, 0.f);
            Ms[r * 128 + (((ncol >> 3) ^ (r & 7)) * 8) + (ncol & 7)] = (_Float16)v;
        }
    }
    __syncthreads();

#pragma unroll
    for (int p = 0; p < 4; ++p) {
        int sid = p * 256 + tid;
        int r = sid >> 4, s = sid & 15;
        uint4 v = *reinterpret_cast<const uint4*>(tm2 + (size_t)r * 128 + s * 8);
        *reinterpret_cast<uint4*>(&Ws[r * 128 + ((s ^ (r & 7)) * 8)]) = v;
    }
    __syncthreads();

    // phase 3: z = M @ mW2 + b2 (F=64)
    half8 am[4];
#pragma unroll
    for (int kk = 0; kk < 4; ++kk)
        am[kk] = *reinterpret_cast<const half8*>(&Ms[mrow * 128 + (((kk * 4 + kg) ^ (mrow & 7)) * 8)]);

#pragma unroll
    for (int ct = 0; ct < 4; ++ct) {
        const int ncol = ct * 16 + (lane & 15);
        f32x4 acc = {0.f, 0.f, 0.f, 0.f};
#pragma unroll
        for (int kk = 0; kk < 4; ++kk) {
            half8 b = *reinterpret_cast<const half8*>(&Ws[ncol * 128 + (((kk * 4 + kg) ^ (ncol & 7)) * 8)]);
            acc = __builtin_amdgcn_mfma_f32_16x16x32_f16(am[kk], b, acc, 0, 0, 0);
        }
        const float bias = b2[ncol];
        const int grow = row0 + wv * 16 + kg * 4;
#pragma unroll
        for (int j = 0; j < 4; ++j)
            if (grow + j < nrows)
                z[(size_t)(grow + j) * 64 + ncol] = (_Float16)((float)acc[j] + bias);
    }
}

// ============ MFMA GEMM: h2 = hmid @ gW2 (fp16 in/out), F=64 ============
__global__ __launch_bounds__(256) void k_mm64(const _Float16* __restrict__ A,
                                              const _Float16* __restrict__ Wt,
                                              _Float16* __restrict__ C, int nrows) {
    __shared__ _Float16 As[64 * 128];
    __shared__ _Float16 Ws[64 * 128];
    const int tid  = threadIdx.x;
    const int row0 = blockIdx.x * 64;

#pragma unroll
    for (int p = 0; p < 4; ++p) {
        int sid = p * 256 + tid;
        int r = sid >> 4, s = sid & 15;
        int gr = row0 + r;
        uint4 v = make_uint4(0, 0, 0, 0);
        if (gr < nrows) v = *reinterpret_cast<const uint4*>(A + (size_t)gr * 128 + s * 8);
        *reinterpret_cast<uint4*>(&As[r * 128 + ((s ^ (r & 7)) * 8)]) = v;
    }
#pragma unroll
    for (int p = 0; p < 4; ++p) {
        int sid = p * 256 + tid;
        int r = sid >> 4, s = sid & 15;
        uint4 v = *reinterpret_cast<const uint4*>(Wt + (size_t)r * 128 + s * 8);
        *reinterpret_cast<uint4*>(&Ws[r * 128 + ((s ^ (r & 7)) * 8)]) = v;
    }
    __syncthreads();

    const int lane = tid & 63;
    const int wv   = tid >> 6;
    const int mrow = wv * 16 + (lane & 15);
    const int kg   = lane >> 4;

    half8 a[4];
#pragma unroll
    for (int kk = 0; kk < 4; ++kk)
        a[kk] = *reinterpret_cast<const half8*>(&As[mrow * 128 + (((kk * 4 + kg) ^ (mrow & 7)) * 8)]);

#pragma unroll
    for (int ct = 0; ct < 4; ++ct) {
        const int ncol = ct * 16 + (lane & 15);
        f32x4 acc = {0.f, 0.f, 0.f, 0.f};
#pragma unroll
        for (int kk = 0; kk < 4; ++kk) {
            half8 b = *reinterpret_cast<const half8*>(&Ws[ncol * 128 + (((kk * 4 + kg) ^ (ncol & 7)) * 8)]);
            acc = __builtin_amdgcn_mfma_f32_16x16x32_f16(a[kk], b, acc, 0, 0, 0);
        }
        const int grow = row0 + wv * 16 + kg * 4;
#pragma unroll
        for (int j = 0; j < 4; ++j)
            if (grow + j < nrows)
                C[(size_t)(grow + j) * 64 + ncol] = (_Float16)acc[j];
    }
}

// ================= gather aggregation: 4 edges in flight per wave =================
// layer 1: F=128. 16-lane groups, half8 (16B) per lane per edge row.
__global__ __launch_bounds__(256) void k_agg1(const int* __restrict__ rp,
                                              const int* __restrict__ csr,
                                              const float* __restrict__ dis,
                                              const _Float16* __restrict__ h1,
                                              const float* __restrict__ b,
                                              _Float16* __restrict__ out, int n) {
    const int tid  = threadIdx.x;
    const int node = blockIdx.x * 4 + (tid >> 6);
    if (node >= n) return;
    const int lane = tid & 63;
    const int g    = lane >> 4;          // edge group 0..3
    const int c0   = (lane & 15) * 8;    // 8 feature cols per lane
    const int start = rp[node], end = rp[node + 1];

    float acc[8];
#pragma unroll
    for (int k = 0; k < 8; ++k) acc[k] = 0.f;

    int j = start + g;
    for (; j + 4 < end; j += 8) {
        int s0 = csr[j];
        int s1 = csr[j + 4];
        float w0 = dis[s0];
        float w1 = dis[s1];
        half8 v0 = *reinterpret_cast<const half8*>(h1 + (size_t)s0 * 128 + c0);
        half8 v1 = *reinterpret_cast<const half8*>(h1 + (size_t)s1 * 128 + c0);
#pragma unroll
        for (int k = 0; k < 8; ++k)
            acc[k] += w0 * (float)v0[k] + w1 * (float)v1[k];
    }
    if (j < end) {
        int s0 = csr[j];
        float w0 = dis[s0];
        half8 v0 = *reinterpret_cast<const half8*>(h1 + (size_t)s0 * 128 + c0);
#pragma unroll
        for (int k = 0; k < 8; ++k) acc[k] += w0 * (float)v0[k];
    }

#pragma unroll
    for (int k = 0; k < 8; ++k) {
        acc[k] += __shfl_xor(acc[k], 16);
        acc[k] += __shfl_xor(acc[k], 32);
    }

    if (g == 0) {
        const float dd = dis[node];
        const float di = 1.0f / (float)(end - start + 1);
        half8 hv = *reinterpret_cast<const half8*>(h1 + (size_t)node * 128 + c0);
        const float4 bv0 = *reinterpret_cast<const float4*>(b + c0);
        const float4 bv1 = *reinterpret_cast<const float4*>(b + c0 + 4);
        const float bb[8] = {bv0.x, bv0.y, bv0.z, bv0.w, bv1.x, bv1.y, bv1.z, bv1.w};
        half8 o;
#pragma unroll
        for (int k = 0; k < 8; ++k)
            o[k] = (_Float16)fmaxf(dd * acc[k] + (float)hv[k] * di + bb[k], 0.f);
        *reinterpret_cast<half8*>(out + (size_t)node * 128 + c0) = o;
    }
}

// layer 2 + final fuse: F=64. 16-lane groups, half4 (8B) per lane per edge row.
__global__ __launch_bounds__(256) void k_agg2(const int* __restrict__ rp,
                                              const int* __restrict__ csr,
                                              const float* __restrict__ dis,
                                              const _Float16* __restrict__ h2,
                                              const float* __restrict__ b,
                                              const _Float16* __restrict__ zmlp,
                                              float* __restrict__ out, int n) {
    const int tid  = threadIdx.x;
    const int node = blockIdx.x * 4 + (tid >> 6);
    if (node >= n) return;
    const int lane = tid & 63;
    const int g    = lane >> 4;
    const int c0   = (lane & 15) * 4;
    const int start = rp[node], end = rp[node + 1];

    float acc[4];
#pragma unroll
    for (int k = 0; k < 4; ++k) acc[k] = 0.f;

    int j = start + g;
    for (; j + 4 < end; j += 8) {
        int s0 = csr[j];
        int s1 = csr[j + 4];
        float w0 = dis[s0];
        float w1 = dis[s1];
        half4 v0 = *reinterpret_cast<const half4*>(h2 + (size_t)s0 * 64 + c0);
        half4 v1 = *reinterpret_cast<const half4*>(h2 + (size_t)s1 * 64 + c0);
#pragma unroll
        for (int k = 0; k < 4; ++k)
            acc[k] += w0 * (float)v0[k] + w1 * (float)v1[k];
    }
    if (j < end) {
        int s0 = csr[j];
        float w0 = dis[s0];
        half4 v0 = *reinterpret_cast<const half4*>(h2 + (size_t)s0 * 64 + c0);
#pragma unroll
        for (int k = 0; k < 4; ++k) acc[k] += w0 * (float)v0[k];
    }

#pragma unroll
    for (int k = 0; k < 4; ++k) {
        acc[k] += __shfl_xor(acc[k], 16);
        acc[k] += __shfl_xor(acc[k], 32);
    }

    if (g == 0) {
        const float dd = dis[node];
        const float di = 1.0f / (float)(end - start + 1);
        half4 hv = *reinterpret_cast<const half4*>(h2 + (size_t)node * 64 + c0);
        half4 zm = *reinterpret_cast<const half4*>(zmlp + (size_t)node * 64 + c0);
        const float4 bv = *reinterpret_cast<const float4*>(b + c0);
        const float bb[4] = {bv.x, bv.y, bv.z, bv.w};
        float4 o;
        float* op = &o.x;
#pragma unroll
        for (int k = 0; k < 4; ++k)
            op[k] = 0.5f * ((dd * acc[k] + (float)hv[k] * di + bb[k]) + (float)zm[k]);
        *reinterpret_cast<float4*>(out + (size_t)node * 64 + c0) = o;
    }
}

extern "C" void kernel_launch(void* const* d_in, const int* in_sizes, int n_in,
                              void* d_out, int out_size, void* d_ws, size_t ws_size,
                              hipStream_t stream) {
    const float* x      = (const float*)d_in[0];
    const int* edge_idx = (const int*)d_in[1];
    const float* gnn_W1 = (const float*)d_in[2];
    const float* gnn_b1 = (const float*)d_in[3];
    const float* gnn_W2 = (const float*)d_in[4];
    const float* gnn_b2 = (const float*)d_in[5];
    const float* mlp_W1 = (const float*)d_in[6];
    const float* mlp_b1 = (const float*)d_in[7];
    const float* mlp_W2 = (const float*)d_in[8];
    const float* mlp_b2 = (const float*)d_in[9];
    float* out = (float*)d_out;

    const int N = in_sizes[0] / IN_F;
    const int E = in_sizes[1] / 2;
    const int* src = edge_idx;
    const int* dst = edge_idx + E;

    const int NB = (N + 255) >> 8;   // 256-node buckets (<= 512 for N <= 131072)

    // ---- workspace layout ----
    char* wp = (char*)d_ws;
    int* row_ptr   = (int*)wp;            wp += ((size_t)N + 4) * sizeof(int);
    int* bbase     = (int*)wp;            wp += 516 * sizeof(int);
    int* bcursor   = (int*)wp;            wp += 512 * sizeof(int);
    int* bcount    = (int*)wp;            wp += 512 * sizeof(int);
    int* csr       = (int*)wp;            wp += (size_t)E * sizeof(int);
    unsigned* recs = (unsigned*)wp;       wp += (size_t)E * sizeof(unsigned);
    float* dis     = (float*)wp;          wp += (size_t)N * sizeof(float);
    _Float16* tg1  = (_Float16*)wp;       wp += 16384 * sizeof(_Float16);
    _Float16* tm1  = (_Float16*)wp;       wp += 16384 * sizeof(_Float16);
    _Float16* tm2  = (_Float16*)wp;       wp += 8192 * sizeof(_Float16);
    _Float16* tg2  = (_Float16*)wp;       wp += 8192 * sizeof(_Float16);
    _Float16* h1   = (_Float16*)wp;       wp += (size_t)N * 128 * sizeof(_Float16);
    _Float16* hmid = (_Float16*)wp;       wp += (size_t)N * 128 * sizeof(_Float16);
    _Float16* h2   = (_Float16*)wp;       wp += (size_t)N * 64 * sizeof(_Float16);
    _Float16* zmlp = (_Float16*)wp;       wp += (size_t)N * 64 * sizeof(_Float16);

    // ---- weight prep ----
    k_prep_w<<<192, 256, 0, stream>>>(gnn_W1, mlp_W1, mlp_W2, gnn_W2, tg1, tm1, tm2, tg2);

    // ---- bucketed CSR build (radix pass + LDS-sorted fill) ----
    hipMemsetAsync(bcount, 0, 512 * sizeof(int), stream);
    const int mvblocks = (E + 8191) / 8192;
    kb_count<<<mvblocks, 1024, 0, stream>>>(dst, bcount, E);
    k_scanb<<<1, 512, 0, stream>>>(bcount, bbase, bcursor, NB);
    kb_move<<<mvblocks, 1024, 0, stream>>>(src, dst, bcursor, recs, E);
    kb_fill_lds<<<NB, 256, 0, stream>>>(recs, bbase, row_ptr, dis, csr, N);

    const int gblocks = (N + 63) / 64;

    // ---- fused: h1 = x@gW1, zmlp = MLP(x) (one x pass) ----
    k_dual_mfma<<<gblocks, 256, 0, stream>>>(x, tg1, tm1, tm2, mlp_b1, mlp_b2, h1, zmlp, N);

    // ---- GNN layer 1 aggregation ----
    k_agg1<<<(N + 3) / 4, 256, 0, stream>>>(row_ptr, csr, dis, h1, gnn_b1, hmid, N);

    // ---- h2 = hmid @ gW2 (MFMA) ----
    k_mm64<<<gblocks, 256, 0, stream>>>(hmid, tg2, h2, N);

    // ---- layer-2 aggregation fused with final mix ----
    k_agg2<<<(N + 3) / 4, 256, 0, stream>>>(row_ptr, csr, dis, h2, gnn_b2, zmlp, out, N);
}